// Round 1
// baseline (860.984 us; speedup 1.0000x reference)
//
#include <hip/hip_runtime.h>
#include <math.h>
#include <stdint.h>

// ---------------------------------------------------------------------------
// MultiHeadAttention, softmax over HEAD axis (dim=1), bf16 MFMA pipeline.
// B=4, S=2048, DIM=1024, H=8, DH=128.
//   q = (Q WQ^T) * 1/sqrt(128)   [b,s,1024] bf16 (scale folded in epilogue)
//   k =  K WK^T                  [b,s,1024] bf16
//   vt = (V WV^T) transposed ->  [b,h,dh,s] bf16 (epilogue transpose)
//   attn[b,h,q,k] = exp(s)/sum_h exp(s);  ctx[b,s,h*128+d] = sum_k attn * v
//   out = ctx WO^T               fp32 -> d_out
// ---------------------------------------------------------------------------

typedef __attribute__((ext_vector_type(8))) __bf16 bf16x8;
typedef __attribute__((ext_vector_type(4))) __bf16 bf16x4;
typedef __attribute__((ext_vector_type(4))) float  f32x4;

__device__ __forceinline__ f32x4 mfma16(bf16x8 a, bf16x8 b, f32x4 c) {
    return __builtin_amdgcn_mfma_f32_16x16x32_bf16(a, b, c, 0, 0, 0);
}

// async global->LDS, 16B per lane; LDS dest must be wave-uniform-base + lane*16
__device__ __forceinline__ void cp16(void* lds, const void* g) {
    __builtin_amdgcn_global_load_lds(
        (__attribute__((address_space(1))) void*)(void*)(const_cast<void*>(g)),
        (__attribute__((address_space(3))) void*)lds,
        16, 0, 0);
}

// ---------------------------------------------------------------------------
__global__ void cast_f32_to_bf16(const float* __restrict__ src,
                                 __bf16* __restrict__ dst, int n4) {
    int i = blockIdx.x * blockDim.x + threadIdx.x;
    const int stride = gridDim.x * blockDim.x;
    for (; i < n4; i += stride) {
        float4 f = ((const float4*)src)[i];
        bf16x4 o;
        o[0] = (__bf16)f.x; o[1] = (__bf16)f.y; o[2] = (__bf16)f.z; o[3] = (__bf16)f.w;
        ((bf16x4*)dst)[i] = o;
    }
}

// ---------------------------------------------------------------------------
// C[8192,1024] = A[8192,1024] * Bt[1024,1024]^T   (Bt stored [N,K] row-major)
// MODE 0: bf16 out, natural [m,n], * scale
// MODE 1: f32 out, natural [m,n]
// MODE 2: bf16 out, v-transpose: out[((b*8+h)*128+dh)*2048 + s]
template<int MODE>
__global__ __launch_bounds__(256, 2) void gemm_bt(const __bf16* __restrict__ A,
                                                  const __bf16* __restrict__ Bt,
                                                  void* __restrict__ out,
                                                  float scale)
{
    __shared__ __bf16 As[128 * 32];
    __shared__ __bf16 Bs[128 * 32];
    const int tid  = threadIdx.x;
    const int lane = tid & 63;
    const int u = lane >> 4, v = lane & 15;   // quad, col-in-tile
    const int w = tid >> 6;
    const int wm = (w >> 1) * 64, wn = (w & 1) * 64;
    const long tM = (long)blockIdx.y * 128;
    const int  tN = blockIdx.x * 128;

    f32x4 acc[4][4];
#pragma unroll
    for (int i = 0; i < 4; ++i)
#pragma unroll
        for (int j = 0; j < 4; ++j) acc[i][j] = (f32x4){0.f, 0.f, 0.f, 0.f};

    // two 16B staging chunks per thread for each of As/Bs
    const int c0 = tid, c1 = tid + 256;
    const int ar0 = c0 >> 2, ak0 = (c0 & 3) * 8;
    const int ar1 = c1 >> 2, ak1 = (c1 & 3) * 8;

    const __bf16* Ab = A  + tM * 1024;
    const __bf16* Bb = Bt + (long)tN * 1024;

    for (int k0 = 0; k0 < 1024; k0 += 32) {
        __syncthreads();
        cp16(&As[ar0 * 32 + ak0], Ab + (long)ar0 * 1024 + k0 + ak0);
        cp16(&As[ar1 * 32 + ak1], Ab + (long)ar1 * 1024 + k0 + ak1);
        cp16(&Bs[ar0 * 32 + ak0], Bb + (long)ar0 * 1024 + k0 + ak0);
        cp16(&Bs[ar1 * 32 + ak1], Bb + (long)ar1 * 1024 + k0 + ak1);
        __syncthreads();

        bf16x8 af[4], bfr[4];
#pragma unroll
        for (int i = 0; i < 4; ++i)
            af[i] = *(const bf16x8*)&As[(wm + i * 16 + v) * 32 + u * 8];
#pragma unroll
        for (int j = 0; j < 4; ++j)
            bfr[j] = *(const bf16x8*)&Bs[(wn + j * 16 + v) * 32 + u * 8];
#pragma unroll
        for (int i = 0; i < 4; ++i)
#pragma unroll
            for (int j = 0; j < 4; ++j)
                acc[i][j] = mfma16(af[i], bfr[j], acc[i][j]);
    }

#pragma unroll
    for (int i = 0; i < 4; ++i) {
#pragma unroll
        for (int j = 0; j < 4; ++j) {
            const long row0 = tM + wm + i * 16 + u * 4;      // + r
            const int  col  = tN + wn + j * 16 + v;
            if (MODE == 0) {
                __bf16* o = (__bf16*)out;
#pragma unroll
                for (int r = 0; r < 4; ++r)
                    o[(row0 + r) * 1024 + col] = (__bf16)(acc[i][j][r] * scale);
            } else if (MODE == 1) {
                float* o = (float*)out;
#pragma unroll
                for (int r = 0; r < 4; ++r)
                    o[(row0 + r) * 1024 + col] = acc[i][j][r];
            } else {
                __bf16* o = (__bf16*)out;
                const int bidx = (int)(row0 >> 11);
                const int s    = (int)(row0 & 2047);          // 4-aligned
                const int h = col >> 7, dh = col & 127;
                bf16x4 pk;
#pragma unroll
                for (int r = 0; r < 4; ++r) pk[r] = (__bf16)acc[i][j][r];
                *(bf16x4*)&o[((long)(bidx * 8 + h) * 128 + dh) * 2048 + s] = pk;
            }
        }
    }
}

// ---------------------------------------------------------------------------
// Fused attention with softmax over heads.
// grid (S/16, B), block 256 (4 waves, 2 heads/wave). K-tile = 32 keys.
// Computes transposed scores sT[key][q] (A = K-tile, B = q-frags) so that the
// P round-trip lands as [q][k]-major for the PV B-operand, and PV computes
// ctxT (A = V^T-tile) whose C-layout gives 4 consecutive feature elems/lane.
__global__ __launch_bounds__(256, 2) void attn_softmax_head(
    const __bf16* __restrict__ qp, const __bf16* __restrict__ kp,
    const __bf16* __restrict__ vt, __bf16* __restrict__ ctx)
{
    __shared__ float part[8 * 256];        // cross-wave head-sum exchange
    __shared__ float pb[4][2][16 * 33];    // per-wave P, [q][k] pad-33

    const int tid  = threadIdx.x;
    const int lane = tid & 63;
    const int w = tid >> 6;
    const int u = lane >> 4, v = lane & 15;
    const int b  = blockIdx.y;
    const int q0 = blockIdx.x * 16;

    // q B-fragments, loaded once: B[k=dh][n=q] -> q(q0+v, kk*32+u*8+j)
    const long qoff = ((long)b * 2048 + q0 + v) * 1024;
    bf16x8 qf[2][4];
#pragma unroll
    for (int hh = 0; hh < 2; ++hh) {
        const int h = 2 * w + hh;
#pragma unroll
        for (int kk = 0; kk < 4; ++kk)
            qf[hh][kk] = *(const bf16x8*)(qp + qoff + h * 128 + kk * 32 + u * 8);
    }

    f32x4 acc[2][8];
#pragma unroll
    for (int hh = 0; hh < 2; ++hh)
#pragma unroll
        for (int dt = 0; dt < 8; ++dt) acc[hh][dt] = (f32x4){0.f, 0.f, 0.f, 0.f};

    for (int kt = 0; kt < 2048; kt += 32) {
        float e[2][2][4];
#pragma unroll
        for (int hh = 0; hh < 2; ++hh) {
            const int h = 2 * w + hh;
#pragma unroll
            for (int t = 0; t < 2; ++t) {
                f32x4 s = (f32x4){0.f, 0.f, 0.f, 0.f};
                const __bf16* kb = kp + ((long)b * 2048 + kt + t * 16 + v) * 1024
                                      + h * 128 + u * 8;
#pragma unroll
                for (int kk = 0; kk < 4; ++kk)
                    s = mfma16(*(const bf16x8*)(kb + kk * 32), qf[hh][kk], s);
                // lane holds sT(key = kt + t*16 + 4u + r, q = q0 + v)
#pragma unroll
                for (int r = 0; r < 4; ++r) e[hh][t][r] = __expf(s[r]);
            }
        }
        // cross-wave denominator: identical (lane,reg)<->(key,q) map in all waves
#pragma unroll
        for (int t = 0; t < 2; ++t)
#pragma unroll
            for (int r = 0; r < 4; ++r)
                part[(t * 4 + r) * 256 + w * 64 + lane] = e[0][t][r] + e[1][t][r];
        __syncthreads();
#pragma unroll
        for (int t = 0; t < 2; ++t)
#pragma unroll
            for (int r = 0; r < 4; ++r) {
                const int j = (t * 4 + r) * 256 + lane;
                const float den = part[j] + part[j + 64] + part[j + 128] + part[j + 192];
                const float rinv = 1.0f / den;
                const int kl = t * 16 + u * 4 + r;
                pb[w][0][v * 33 + kl] = e[0][t][r] * rinv;
                pb[w][1][v * 33 + kl] = e[1][t][r] * rinv;
            }
        // P fragments (wave-private LDS region; in-wave lgkmcnt ordering)
        bf16x8 pf[2];
#pragma unroll
        for (int hh = 0; hh < 2; ++hh)
#pragma unroll
            for (int jj = 0; jj < 8; ++jj)
                pf[hh][jj] = (__bf16)pb[w][hh][v * 33 + u * 8 + jj];
        // PV: ctxT[dh][q] += vt[dh][k] * pT[k][q]
#pragma unroll
        for (int hh = 0; hh < 2; ++hh) {
            const int h = 2 * w + hh;
            const __bf16* vb = vt + ((long)(b * 8 + h) * 128 + v) * 2048 + kt + u * 8;
#pragma unroll
            for (int dt = 0; dt < 8; ++dt)
                acc[hh][dt] = mfma16(*(const bf16x8*)(vb + (long)dt * 16 * 2048),
                                     pf[hh], acc[hh][dt]);
        }
        __syncthreads();   // protect part[] before next iteration's writes
    }

    // lane holds ctxT(dh = dt*16 + 4u + r, q = q0 + v) -> concat layout store
#pragma unroll
    for (int hh = 0; hh < 2; ++hh) {
        const int h = 2 * w + hh;
#pragma unroll
        for (int dt = 0; dt < 8; ++dt) {
            bf16x4 o;
#pragma unroll
            for (int r = 0; r < 4; ++r) o[r] = (__bf16)acc[hh][dt][r];
            *(bf16x4*)(ctx + ((long)b * 2048 + q0 + v) * 1024
                           + h * 128 + dt * 16 + u * 4) = o;
        }
    }
}

// ---------------------------------------------------------------------------
extern "C" void kernel_launch(void* const* d_in, const int* in_sizes, int n_in,
                              void* d_out, int out_size, void* d_ws, size_t ws_size,
                              hipStream_t stream)
{
    const float* Q  = (const float*)d_in[0];
    const float* K  = (const float*)d_in[1];
    const float* V  = (const float*)d_in[2];
    const float* WQ = (const float*)d_in[3];
    const float* WK = (const float*)d_in[4];
    const float* WV = (const float*)d_in[5];
    const float* WO = (const float*)d_in[6];

    // workspace layout (bf16 elems): 4x 1M weights + 4x 8.4M tensors = 75.5 MB
    __bf16* ws = (__bf16*)d_ws;
    __bf16* wq = ws;
    __bf16* wk = wq + 1048576;
    __bf16* wv = wk + 1048576;
    __bf16* wo = wv + 1048576;
    __bf16* xb = wo + 1048576;     // cast buffer; reused as ctx after vt GEMM
    __bf16* qp = xb + 8388608;
    __bf16* kp = qp + 8388608;
    __bf16* vt = kp + 8388608;

    const float qscale = 0.08838834764831845f;   // 1/sqrt(128)

    // weights -> bf16
    cast_f32_to_bf16<<<1024, 256, 0, stream>>>(WQ, wq, 262144);
    cast_f32_to_bf16<<<1024, 256, 0, stream>>>(WK, wk, 262144);
    cast_f32_to_bf16<<<1024, 256, 0, stream>>>(WV, wv, 262144);
    cast_f32_to_bf16<<<1024, 256, 0, stream>>>(WO, wo, 262144);

    dim3 gg(8, 64), gb(256);
    // q projection (scale folded)
    cast_f32_to_bf16<<<4096, 256, 0, stream>>>(Q, xb, 2097152);
    gemm_bt<0><<<gg, gb, 0, stream>>>(xb, wq, qp, qscale);
    // k projection
    cast_f32_to_bf16<<<4096, 256, 0, stream>>>(K, xb, 2097152);
    gemm_bt<0><<<gg, gb, 0, stream>>>(xb, wk, kp, 1.0f);
    // v projection, transposed epilogue -> [b,h,dh,s]
    cast_f32_to_bf16<<<4096, 256, 0, stream>>>(V, xb, 2097152);
    gemm_bt<2><<<gg, gb, 0, stream>>>(xb, wv, vt, 1.0f);

    // fused attention (softmax over heads) -> ctx in xb (xb dead after vt GEMM)
    attn_softmax_head<<<dim3(128, 4), 256, 0, stream>>>(qp, kp, vt, xb);

    // output projection -> fp32 d_out
    gemm_bt<1><<<gg, gb, 0, stream>>>(xb, wo, (float*)d_out, 1.0f);
}

// Round 2
// 860.943 us; speedup vs baseline: 1.0000x; 1.0000x over previous
//
#include <hip/hip_runtime.h>
#include <math.h>
#include <stdint.h>

// ---------------------------------------------------------------------------
// MultiHeadAttention, softmax over HEAD axis (dim=1), bf16 MFMA pipeline.
// B=4, S=2048, DIM=1024, H=8, DH=128.
//   q = (Q WQ^T) * 1/sqrt(128)   [b,s,1024] bf16 (scale folded in epilogue)
//   k =  K WK^T                  [b,s,1024] bf16
//   vt = (V WV^T) transposed ->  [b,h,dh,s] bf16 (epilogue transpose)
//   P[b,h,q,k] = exp(sT)/sum_h exp  via qk_head_softmax (GEMM + in-reg den)
//   ctx = P·V via pv_gemm (pure GEMM), out = ctx WO^T fp32 -> d_out
// ---------------------------------------------------------------------------

typedef __attribute__((ext_vector_type(8))) __bf16 bf16x8;
typedef __attribute__((ext_vector_type(4))) __bf16 bf16x4;
typedef __attribute__((ext_vector_type(4))) float  f32x4;

__device__ __forceinline__ f32x4 mfma16(bf16x8 a, bf16x8 b, f32x4 c) {
    return __builtin_amdgcn_mfma_f32_16x16x32_bf16(a, b, c, 0, 0, 0);
}

// async global->LDS, 16B per lane; LDS dest must be wave-uniform-base + lane*16
__device__ __forceinline__ void cp16(void* lds, const void* g) {
    __builtin_amdgcn_global_load_lds(
        (__attribute__((address_space(1))) void*)(void*)(const_cast<void*>(g)),
        (__attribute__((address_space(3))) void*)lds,
        16, 0, 0);
}

// ---------------------------------------------------------------------------
__global__ void cast_f32_to_bf16(const float* __restrict__ src,
                                 __bf16* __restrict__ dst, int n4) {
    int i = blockIdx.x * blockDim.x + threadIdx.x;
    const int stride = gridDim.x * blockDim.x;
    for (; i < n4; i += stride) {
        float4 f = ((const float4*)src)[i];
        bf16x4 o;
        o[0] = (__bf16)f.x; o[1] = (__bf16)f.y; o[2] = (__bf16)f.z; o[3] = (__bf16)f.w;
        ((bf16x4*)dst)[i] = o;
    }
}

// ---------------------------------------------------------------------------
// C[8192,1024] = A[8192,1024] * Bt[1024,1024]^T   (Bt stored [N,K] row-major)
// MODE 0: bf16 out, natural [m,n], * scale
// MODE 1: f32 out, natural [m,n]
// MODE 2: bf16 out, v-transpose: out[((b*8+h)*128+dh)*2048 + s]
template<int MODE>
__global__ __launch_bounds__(256, 2) void gemm_bt(const __bf16* __restrict__ A,
                                                  const __bf16* __restrict__ Bt,
                                                  void* __restrict__ out,
                                                  float scale)
{
    __shared__ __bf16 As[128 * 32];
    __shared__ __bf16 Bs[128 * 32];
    const int tid  = threadIdx.x;
    const int lane = tid & 63;
    const int u = lane >> 4, v = lane & 15;   // quad, col-in-tile
    const int w = tid >> 6;
    const int wm = (w >> 1) * 64, wn = (w & 1) * 64;
    const long tM = (long)blockIdx.y * 128;
    const int  tN = blockIdx.x * 128;

    f32x4 acc[4][4];
#pragma unroll
    for (int i = 0; i < 4; ++i)
#pragma unroll
        for (int j = 0; j < 4; ++j) acc[i][j] = (f32x4){0.f, 0.f, 0.f, 0.f};

    const int c0 = tid, c1 = tid + 256;
    const int ar0 = c0 >> 2, ak0 = (c0 & 3) * 8;
    const int ar1 = c1 >> 2, ak1 = (c1 & 3) * 8;

    const __bf16* Ab = A  + tM * 1024;
    const __bf16* Bb = Bt + (long)tN * 1024;

    for (int k0 = 0; k0 < 1024; k0 += 32) {
        __syncthreads();
        cp16(&As[ar0 * 32 + ak0], Ab + (long)ar0 * 1024 + k0 + ak0);
        cp16(&As[ar1 * 32 + ak1], Ab + (long)ar1 * 1024 + k0 + ak1);
        cp16(&Bs[ar0 * 32 + ak0], Bb + (long)ar0 * 1024 + k0 + ak0);
        cp16(&Bs[ar1 * 32 + ak1], Bb + (long)ar1 * 1024 + k0 + ak1);
        __syncthreads();

        bf16x8 af[4], bfr[4];
#pragma unroll
        for (int i = 0; i < 4; ++i)
            af[i] = *(const bf16x8*)&As[(wm + i * 16 + v) * 32 + u * 8];
#pragma unroll
        for (int j = 0; j < 4; ++j)
            bfr[j] = *(const bf16x8*)&Bs[(wn + j * 16 + v) * 32 + u * 8];
#pragma unroll
        for (int i = 0; i < 4; ++i)
#pragma unroll
            for (int j = 0; j < 4; ++j)
                acc[i][j] = mfma16(af[i], bfr[j], acc[i][j]);
    }

#pragma unroll
    for (int i = 0; i < 4; ++i) {
#pragma unroll
        for (int j = 0; j < 4; ++j) {
            const long row0 = tM + wm + i * 16 + u * 4;      // + r
            const int  col  = tN + wn + j * 16 + v;
            if (MODE == 0) {
                __bf16* o = (__bf16*)out;
#pragma unroll
                for (int r = 0; r < 4; ++r)
                    o[(row0 + r) * 1024 + col] = (__bf16)(acc[i][j][r] * scale);
            } else if (MODE == 1) {
                float* o = (float*)out;
#pragma unroll
                for (int r = 0; r < 4; ++r)
                    o[(row0 + r) * 1024 + col] = acc[i][j][r];
            } else {
                __bf16* o = (__bf16*)out;
                const int bidx = (int)(row0 >> 11);
                const int s    = (int)(row0 & 2047);          // 4-aligned
                const int h = col >> 7, dh = col & 127;
                bf16x4 pk;
#pragma unroll
                for (int r = 0; r < 4; ++r) pk[r] = (__bf16)acc[i][j][r];
                *(bf16x4*)&o[((long)(bidx * 8 + h) * 128 + dh) * 2048 + s] = pk;
            }
        }
    }
}

// ---------------------------------------------------------------------------
// QK^T for all 8 heads of one (b, 128k x 128q) tile, with head-softmax.
// Per h: sT[k][q] = kp-rows x qp-rows GEMM slice (Kdim=128, 4 BK-iters).
// den accumulates across heads in registers at fixed C-position (k,q).
// exp tiles stored bf16 to P[b][h][q][k] (k contiguous -> bf16x4, which is
// exactly the Bt-operand layout pv_gemm wants), then rescaled by 1/den in
// place (tiles are L2-hot; __threadfence orders same-lane store->load).
__global__ __launch_bounds__(256, 2) void qk_head_softmax(
    const __bf16* __restrict__ kp, const __bf16* __restrict__ qp,
    __bf16* __restrict__ P)
{
    __shared__ __bf16 As[128 * 32];
    __shared__ __bf16 Bs[128 * 32];
    const int tid  = threadIdx.x;
    const int lane = tid & 63;
    const int u = lane >> 4, v = lane & 15;
    const int w = tid >> 6;
    const int wm = (w >> 1) * 64, wn = (w & 1) * 64;
    const int b  = blockIdx.z;
    const int k0 = blockIdx.x * 128;      // M-tile = keys
    const int q0 = blockIdx.y * 128;      // N-tile = queries

    const int c0 = tid, c1 = tid + 256;
    const int ar0 = c0 >> 2, ak0 = (c0 & 3) * 8;
    const int ar1 = c1 >> 2, ak1 = (c1 & 3) * 8;

    const __bf16* Ab = kp + ((long)b * 2048 + k0) * 1024;
    const __bf16* Bb = qp + ((long)b * 2048 + q0) * 1024;

    f32x4 den[4][4];
#pragma unroll
    for (int i = 0; i < 4; ++i)
#pragma unroll
        for (int j = 0; j < 4; ++j) den[i][j] = (f32x4){0.f, 0.f, 0.f, 0.f};

#pragma unroll 1
    for (int h = 0; h < 8; ++h) {
        f32x4 acc[4][4];
#pragma unroll
        for (int i = 0; i < 4; ++i)
#pragma unroll
            for (int j = 0; j < 4; ++j) acc[i][j] = (f32x4){0.f, 0.f, 0.f, 0.f};

#pragma unroll 1
        for (int kb = 0; kb < 4; ++kb) {
            const int co = h * 128 + kb * 32;
            __syncthreads();
            cp16(&As[ar0 * 32 + ak0], Ab + (long)ar0 * 1024 + co + ak0);
            cp16(&As[ar1 * 32 + ak1], Ab + (long)ar1 * 1024 + co + ak1);
            cp16(&Bs[ar0 * 32 + ak0], Bb + (long)ar0 * 1024 + co + ak0);
            cp16(&Bs[ar1 * 32 + ak1], Bb + (long)ar1 * 1024 + co + ak1);
            __syncthreads();

            bf16x8 af[4], bfr[4];
#pragma unroll
            for (int i = 0; i < 4; ++i)
                af[i] = *(const bf16x8*)&As[(wm + i * 16 + v) * 32 + u * 8];
#pragma unroll
            for (int j = 0; j < 4; ++j)
                bfr[j] = *(const bf16x8*)&Bs[(wn + j * 16 + v) * 32 + u * 8];
#pragma unroll
            for (int i = 0; i < 4; ++i)
#pragma unroll
                for (int j = 0; j < 4; ++j)
                    acc[i][j] = mfma16(af[i], bfr[j], acc[i][j]);
        }
        // epilogue for head h: exp, accumulate den, store bf16x4
        __bf16* Ph = P + ((long)(b * 8 + h) * 2048 + q0) * 2048 + k0;
#pragma unroll
        for (int i = 0; i < 4; ++i) {
#pragma unroll
            for (int j = 0; j < 4; ++j) {
                const int kc = wm + i * 16 + u * 4;       // key (tile-local)
                const int qr = wn + j * 16 + v;           // query (tile-local)
                bf16x4 pk;
#pragma unroll
                for (int r = 0; r < 4; ++r) {
                    float e = __expf(acc[i][j][r]);
                    den[i][j][r] += e;
                    pk[r] = (__bf16)e;
                }
                *(bf16x4*)&Ph[(long)qr * 2048 + kc] = pk;
            }
        }
    }

    // normalize the 8 tiles in place (own stores, L2-hot)
#pragma unroll
    for (int i = 0; i < 4; ++i)
#pragma unroll
        for (int j = 0; j < 4; ++j) {
            f32x4 rv;
#pragma unroll
            for (int r = 0; r < 4; ++r) rv[r] = 1.0f / den[i][j][r];
            den[i][j] = rv;
        }
    __threadfence();
#pragma unroll 1
    for (int h = 0; h < 8; ++h) {
        __bf16* Ph = P + ((long)(b * 8 + h) * 2048 + q0) * 2048 + k0;
#pragma unroll
        for (int i = 0; i < 4; ++i) {
#pragma unroll
            for (int j = 0; j < 4; ++j) {
                const int kc = wm + i * 16 + u * 4;
                const int qr = wn + j * 16 + v;
                bf16x4 t = *(bf16x4*)&Ph[(long)qr * 2048 + kc];
#pragma unroll
                for (int r = 0; r < 4; ++r)
                    t[r] = (__bf16)((float)t[r] * den[i][j][r]);
                *(bf16x4*)&Ph[(long)qr * 2048 + kc] = t;
            }
        }
    }
}

// ---------------------------------------------------------------------------
// ctxT[dh][q] = sum_k vt[b,h,dh,k] * P[b,h,q,k]  (Kdim=2048, 64 BK-iters)
// A = vt rows (dh, stride 2048), Bt = P rows (q, stride 2048).
// Epilogue stores ctx in concat layout [b][q][h*128+dh] via bf16x4.
__global__ __launch_bounds__(256, 2) void pv_gemm(
    const __bf16* __restrict__ vt, const __bf16* __restrict__ P,
    __bf16* __restrict__ ctx)
{
    __shared__ __bf16 As[128 * 32];
    __shared__ __bf16 Bs[128 * 32];
    const int tid  = threadIdx.x;
    const int lane = tid & 63;
    const int u = lane >> 4, v = lane & 15;
    const int w = tid >> 6;
    const int wm = (w >> 1) * 64, wn = (w & 1) * 64;
    const int bh = blockIdx.y;            // b*8+h
    const int b  = bh >> 3, h = bh & 7;
    const int q0 = blockIdx.x * 128;      // N-tile

    const int c0 = tid, c1 = tid + 256;
    const int ar0 = c0 >> 2, ak0 = (c0 & 3) * 8;
    const int ar1 = c1 >> 2, ak1 = (c1 & 3) * 8;

    const __bf16* Ab = vt + (long)bh * 128 * 2048;
    const __bf16* Bb = P  + ((long)bh * 2048 + q0) * 2048;

    f32x4 acc[4][4];
#pragma unroll
    for (int i = 0; i < 4; ++i)
#pragma unroll
        for (int j = 0; j < 4; ++j) acc[i][j] = (f32x4){0.f, 0.f, 0.f, 0.f};

    for (int k0 = 0; k0 < 2048; k0 += 32) {
        __syncthreads();
        cp16(&As[ar0 * 32 + ak0], Ab + (long)ar0 * 2048 + k0 + ak0);
        cp16(&As[ar1 * 32 + ak1], Ab + (long)ar1 * 2048 + k0 + ak1);
        cp16(&Bs[ar0 * 32 + ak0], Bb + (long)ar0 * 2048 + k0 + ak0);
        cp16(&Bs[ar1 * 32 + ak1], Bb + (long)ar1 * 2048 + k0 + ak1);
        __syncthreads();

        bf16x8 af[4], bfr[4];
#pragma unroll
        for (int i = 0; i < 4; ++i)
            af[i] = *(const bf16x8*)&As[(wm + i * 16 + v) * 32 + u * 8];
#pragma unroll
        for (int j = 0; j < 4; ++j)
            bfr[j] = *(const bf16x8*)&Bs[(wn + j * 16 + v) * 32 + u * 8];
#pragma unroll
        for (int i = 0; i < 4; ++i)
#pragma unroll
            for (int j = 0; j < 4; ++j)
                acc[i][j] = mfma16(af[i], bfr[j], acc[i][j]);
    }

#pragma unroll
    for (int i = 0; i < 4; ++i) {
#pragma unroll
        for (int j = 0; j < 4; ++j) {
            const int dh0 = wm + i * 16 + u * 4;          // 4-consec feature
            const int q   = q0 + wn + j * 16 + v;
            bf16x4 pk;
#pragma unroll
            for (int r = 0; r < 4; ++r) pk[r] = (__bf16)acc[i][j][r];
            *(bf16x4*)&ctx[((long)b * 2048 + q) * 1024 + h * 128 + dh0] = pk;
        }
    }
}

// ---------------------------------------------------------------------------
// Fallback (round-1 fused attention) in case ws_size < 344 MB.
__global__ __launch_bounds__(256, 2) void attn_softmax_head(
    const __bf16* __restrict__ qp, const __bf16* __restrict__ kp,
    const __bf16* __restrict__ vt, __bf16* __restrict__ ctx)
{
    __shared__ float part[8 * 256];
    __shared__ float pb[4][2][16 * 33];

    const int tid  = threadIdx.x;
    const int lane = tid & 63;
    const int w = tid >> 6;
    const int u = lane >> 4, v = lane & 15;
    const int b  = blockIdx.y;
    const int q0 = blockIdx.x * 16;

    const long qoff = ((long)b * 2048 + q0 + v) * 1024;
    bf16x8 qf[2][4];
#pragma unroll
    for (int hh = 0; hh < 2; ++hh) {
        const int h = 2 * w + hh;
#pragma unroll
        for (int kk = 0; kk < 4; ++kk)
            qf[hh][kk] = *(const bf16x8*)(qp + qoff + h * 128 + kk * 32 + u * 8);
    }

    f32x4 acc[2][8];
#pragma unroll
    for (int hh = 0; hh < 2; ++hh)
#pragma unroll
        for (int dt = 0; dt < 8; ++dt) acc[hh][dt] = (f32x4){0.f, 0.f, 0.f, 0.f};

    for (int kt = 0; kt < 2048; kt += 32) {
        float e[2][2][4];
#pragma unroll
        for (int hh = 0; hh < 2; ++hh) {
            const int h = 2 * w + hh;
#pragma unroll
            for (int t = 0; t < 2; ++t) {
                f32x4 s = (f32x4){0.f, 0.f, 0.f, 0.f};
                const __bf16* kb = kp + ((long)b * 2048 + kt + t * 16 + v) * 1024
                                      + h * 128 + u * 8;
#pragma unroll
                for (int kk = 0; kk < 4; ++kk)
                    s = mfma16(*(const bf16x8*)(kb + kk * 32), qf[hh][kk], s);
#pragma unroll
                for (int r = 0; r < 4; ++r) e[hh][t][r] = __expf(s[r]);
            }
        }
#pragma unroll
        for (int t = 0; t < 2; ++t)
#pragma unroll
            for (int r = 0; r < 4; ++r)
                part[(t * 4 + r) * 256 + w * 64 + lane] = e[0][t][r] + e[1][t][r];
        __syncthreads();
#pragma unroll
        for (int t = 0; t < 2; ++t)
#pragma unroll
            for (int r = 0; r < 4; ++r) {
                const int j = (t * 4 + r) * 256 + lane;
                const float den = part[j] + part[j + 64] + part[j + 128] + part[j + 192];
                const float rinv = 1.0f / den;
                const int kl = t * 16 + u * 4 + r;
                pb[w][0][v * 33 + kl] = e[0][t][r] * rinv;
                pb[w][1][v * 33 + kl] = e[1][t][r] * rinv;
            }
        bf16x8 pf[2];
#pragma unroll
        for (int hh = 0; hh < 2; ++hh)
#pragma unroll
            for (int jj = 0; jj < 8; ++jj)
                pf[hh][jj] = (__bf16)pb[w][hh][v * 33 + u * 8 + jj];
#pragma unroll
        for (int hh = 0; hh < 2; ++hh) {
            const int h = 2 * w + hh;
            const __bf16* vb = vt + ((long)(b * 8 + h) * 128 + v) * 2048 + kt + u * 8;
#pragma unroll
            for (int dt = 0; dt < 8; ++dt)
                acc[hh][dt] = mfma16(*(const bf16x8*)(vb + (long)dt * 16 * 2048),
                                     pf[hh], acc[hh][dt]);
        }
        __syncthreads();
    }

#pragma unroll
    for (int hh = 0; hh < 2; ++hh) {
        const int h = 2 * w + hh;
#pragma unroll
        for (int dt = 0; dt < 8; ++dt) {
            bf16x4 o;
#pragma unroll
            for (int r = 0; r < 4; ++r) o[r] = (__bf16)acc[hh][dt][r];
            *(bf16x4*)(ctx + ((long)b * 2048 + q0 + v) * 1024
                           + h * 128 + dt * 16 + u * 4) = o;
        }
    }
}

// ---------------------------------------------------------------------------
extern "C" void kernel_launch(void* const* d_in, const int* in_sizes, int n_in,
                              void* d_out, int out_size, void* d_ws, size_t ws_size,
                              hipStream_t stream)
{
    const float* Q  = (const float*)d_in[0];
    const float* K  = (const float*)d_in[1];
    const float* V  = (const float*)d_in[2];
    const float* WQ = (const float*)d_in[3];
    const float* WK = (const float*)d_in[4];
    const float* WV = (const float*)d_in[5];
    const float* WO = (const float*)d_in[6];

    // workspace layout (bf16 elems):
    //   4x 1M weights (8 MB) + 4x 8.4M tensors (67 MB) [+ 134M P (268 MB)]
    __bf16* ws = (__bf16*)d_ws;
    __bf16* wq = ws;
    __bf16* wk = wq + 1048576;
    __bf16* wv = wk + 1048576;
    __bf16* wo = wv + 1048576;
    __bf16* xb = wo + 1048576;     // cast buffer; reused as ctx
    __bf16* qp = xb + 8388608;
    __bf16* kp = qp + 8388608;
    __bf16* vt = kp + 8388608;
    __bf16* pb = vt + 8388608;     // P buffer (268 MB), only if ws allows

    const float qscale = 0.08838834764831845f;   // 1/sqrt(128)
    const size_t WS_NEED = 343932928ULL;         // 75.5 MB + 268.4 MB

    cast_f32_to_bf16<<<1024, 256, 0, stream>>>(WQ, wq, 262144);
    cast_f32_to_bf16<<<1024, 256, 0, stream>>>(WK, wk, 262144);
    cast_f32_to_bf16<<<1024, 256, 0, stream>>>(WV, wv, 262144);
    cast_f32_to_bf16<<<1024, 256, 0, stream>>>(WO, wo, 262144);

    dim3 gg(8, 64), gb(256);
    cast_f32_to_bf16<<<4096, 256, 0, stream>>>(Q, xb, 2097152);
    gemm_bt<0><<<gg, gb, 0, stream>>>(xb, wq, qp, qscale);
    cast_f32_to_bf16<<<4096, 256, 0, stream>>>(K, xb, 2097152);
    gemm_bt<0><<<gg, gb, 0, stream>>>(xb, wk, kp, 1.0f);
    cast_f32_to_bf16<<<4096, 256, 0, stream>>>(V, xb, 2097152);
    gemm_bt<2><<<gg, gb, 0, stream>>>(xb, wv, vt, 1.0f);

    if (ws_size >= WS_NEED) {
        // GEMM-decomposed attention
        qk_head_softmax<<<dim3(16, 16, 4), 256, 0, stream>>>(kp, qp, pb);
        pv_gemm<<<dim3(16, 32), 256, 0, stream>>>(vt, pb, xb);
    } else {
        attn_softmax_head<<<dim3(128, 4), 256, 0, stream>>>(qp, kp, vt, xb);
    }

    gemm_bt<1><<<gg, gb, 0, stream>>>(xb, wo, (float*)d_out, 1.0f);
}

// Round 3
// 735.974 us; speedup vs baseline: 1.1699x; 1.1698x over previous
//
#include <hip/hip_runtime.h>
#include <math.h>
#include <stdint.h>

// ---------------------------------------------------------------------------
// MultiHeadAttention, softmax over HEAD axis (dim=1), bf16 MFMA pipeline.
// B=4, S=2048, DIM=1024, H=8, DH=128.
//   q = (Q WQ^T) * 1/sqrt(128)   [b,s,1024] bf16 (scale folded in epilogue)
//   k =  K WK^T                  [b,s,1024] bf16
//   vt = (V WV^T) transposed ->  [b,h,dh,s] bf16 (epilogue transpose)
//   P[bloc,h,q,k] = exp(sT)/sum_h exp  via qk_head_softmax (GEMM + in-reg den)
//   ctx = P·V via pv_gemm (pure GEMM), out = ctx WO^T fp32 -> d_out
// P buffer is sized adaptively from ws_size: (b, q-chunk) tiles are fully
// independent under head-softmax, so we loop chunks with no accumulation.
// ---------------------------------------------------------------------------

typedef __attribute__((ext_vector_type(8))) __bf16 bf16x8;
typedef __attribute__((ext_vector_type(4))) __bf16 bf16x4;
typedef __attribute__((ext_vector_type(4))) float  f32x4;

__device__ __forceinline__ f32x4 mfma16(bf16x8 a, bf16x8 b, f32x4 c) {
    return __builtin_amdgcn_mfma_f32_16x16x32_bf16(a, b, c, 0, 0, 0);
}

// async global->LDS, 16B per lane; LDS dest must be wave-uniform-base + lane*16
__device__ __forceinline__ void cp16(void* lds, const void* g) {
    __builtin_amdgcn_global_load_lds(
        (__attribute__((address_space(1))) void*)(void*)(const_cast<void*>(g)),
        (__attribute__((address_space(3))) void*)lds,
        16, 0, 0);
}

// ---------------------------------------------------------------------------
__global__ void cast_f32_to_bf16(const float* __restrict__ src,
                                 __bf16* __restrict__ dst, int n4) {
    int i = blockIdx.x * blockDim.x + threadIdx.x;
    const int stride = gridDim.x * blockDim.x;
    for (; i < n4; i += stride) {
        float4 f = ((const float4*)src)[i];
        bf16x4 o;
        o[0] = (__bf16)f.x; o[1] = (__bf16)f.y; o[2] = (__bf16)f.z; o[3] = (__bf16)f.w;
        ((bf16x4*)dst)[i] = o;
    }
}

// ---------------------------------------------------------------------------
// C[8192,1024] = A[8192,1024] * Bt[1024,1024]^T   (Bt stored [N,K] row-major)
// MODE 0: bf16 out, natural [m,n], * scale
// MODE 1: f32 out, natural [m,n]
// MODE 2: bf16 out, v-transpose: out[((b*8+h)*128+dh)*2048 + s]
template<int MODE>
__global__ __launch_bounds__(256, 2) void gemm_bt(const __bf16* __restrict__ A,
                                                  const __bf16* __restrict__ Bt,
                                                  void* __restrict__ out,
                                                  float scale)
{
    __shared__ __bf16 As[128 * 32];
    __shared__ __bf16 Bs[128 * 32];
    const int tid  = threadIdx.x;
    const int lane = tid & 63;
    const int u = lane >> 4, v = lane & 15;   // quad, col-in-tile
    const int w = tid >> 6;
    const int wm = (w >> 1) * 64, wn = (w & 1) * 64;
    const long tM = (long)blockIdx.y * 128;
    const int  tN = blockIdx.x * 128;

    f32x4 acc[4][4];
#pragma unroll
    for (int i = 0; i < 4; ++i)
#pragma unroll
        for (int j = 0; j < 4; ++j) acc[i][j] = (f32x4){0.f, 0.f, 0.f, 0.f};

    const int c0 = tid, c1 = tid + 256;
    const int ar0 = c0 >> 2, ak0 = (c0 & 3) * 8;
    const int ar1 = c1 >> 2, ak1 = (c1 & 3) * 8;

    const __bf16* Ab = A  + tM * 1024;
    const __bf16* Bb = Bt + (long)tN * 1024;

    for (int k0 = 0; k0 < 1024; k0 += 32) {
        __syncthreads();
        cp16(&As[ar0 * 32 + ak0], Ab + (long)ar0 * 1024 + k0 + ak0);
        cp16(&As[ar1 * 32 + ak1], Ab + (long)ar1 * 1024 + k0 + ak1);
        cp16(&Bs[ar0 * 32 + ak0], Bb + (long)ar0 * 1024 + k0 + ak0);
        cp16(&Bs[ar1 * 32 + ak1], Bb + (long)ar1 * 1024 + k0 + ak1);
        __syncthreads();

        bf16x8 af[4], bfr[4];
#pragma unroll
        for (int i = 0; i < 4; ++i)
            af[i] = *(const bf16x8*)&As[(wm + i * 16 + v) * 32 + u * 8];
#pragma unroll
        for (int j = 0; j < 4; ++j)
            bfr[j] = *(const bf16x8*)&Bs[(wn + j * 16 + v) * 32 + u * 8];
#pragma unroll
        for (int i = 0; i < 4; ++i)
#pragma unroll
            for (int j = 0; j < 4; ++j)
                acc[i][j] = mfma16(af[i], bfr[j], acc[i][j]);
    }

#pragma unroll
    for (int i = 0; i < 4; ++i) {
#pragma unroll
        for (int j = 0; j < 4; ++j) {
            const long row0 = tM + wm + i * 16 + u * 4;      // + r
            const int  col  = tN + wn + j * 16 + v;
            if (MODE == 0) {
                __bf16* o = (__bf16*)out;
#pragma unroll
                for (int r = 0; r < 4; ++r)
                    o[(row0 + r) * 1024 + col] = (__bf16)(acc[i][j][r] * scale);
            } else if (MODE == 1) {
                float* o = (float*)out;
#pragma unroll
                for (int r = 0; r < 4; ++r)
                    o[(row0 + r) * 1024 + col] = acc[i][j][r];
            } else {
                __bf16* o = (__bf16*)out;
                const int bidx = (int)(row0 >> 11);
                const int s    = (int)(row0 & 2047);          // 4-aligned
                const int h = col >> 7, dh = col & 127;
                bf16x4 pk;
#pragma unroll
                for (int r = 0; r < 4; ++r) pk[r] = (__bf16)acc[i][j][r];
                *(bf16x4*)&o[((long)(bidx * 8 + h) * 128 + dh) * 2048 + s] = pk;
            }
        }
    }
}

// ---------------------------------------------------------------------------
// QK^T for all 8 heads of one (b, 128k x 128q) tile, with head-softmax.
// Chunked: covers batches [b_base, b_base+gridDim.z), queries
// [q_base, q_base + gridDim.y*128). P indexed with chunk-local (bloc, q).
// Per h: sT[k][q] = kp-rows x qp-rows GEMM slice (Kdim=128, 4 BK-iters).
// den accumulates across heads in registers at fixed C-position (k,q).
// exp tiles stored bf16 to P[bloc][h][q][k] (k contiguous -> bf16x4 = the
// Bt-operand layout pv_gemm wants), then rescaled by 1/den in place
// (same-lane store->load; __threadfence orders).
__global__ __launch_bounds__(256, 2) void qk_head_softmax(
    const __bf16* __restrict__ kp, const __bf16* __restrict__ qp,
    __bf16* __restrict__ P, int b_base, int q_base)
{
    __shared__ __bf16 As[128 * 32];
    __shared__ __bf16 Bs[128 * 32];
    const int tid  = threadIdx.x;
    const int lane = tid & 63;
    const int u = lane >> 4, v = lane & 15;
    const int w = tid >> 6;
    const int wm = (w >> 1) * 64, wn = (w & 1) * 64;
    const int bloc = blockIdx.z;
    const int b    = b_base + bloc;
    const int k0   = blockIdx.x * 128;            // M-tile = keys
    const int q0l  = blockIdx.y * 128;            // N-tile = queries (local)
    const int q0g  = q_base + q0l;                // global query base
    const long Cq  = (long)gridDim.y * 128;       // chunk query extent

    const int c0 = tid, c1 = tid + 256;
    const int ar0 = c0 >> 2, ak0 = (c0 & 3) * 8;
    const int ar1 = c1 >> 2, ak1 = (c1 & 3) * 8;

    const __bf16* Ab = kp + ((long)b * 2048 + k0) * 1024;
    const __bf16* Bb = qp + ((long)b * 2048 + q0g) * 1024;

    f32x4 den[4][4];
#pragma unroll
    for (int i = 0; i < 4; ++i)
#pragma unroll
        for (int j = 0; j < 4; ++j) den[i][j] = (f32x4){0.f, 0.f, 0.f, 0.f};

#pragma unroll 1
    for (int h = 0; h < 8; ++h) {
        f32x4 acc[4][4];
#pragma unroll
        for (int i = 0; i < 4; ++i)
#pragma unroll
            for (int j = 0; j < 4; ++j) acc[i][j] = (f32x4){0.f, 0.f, 0.f, 0.f};

#pragma unroll 1
        for (int kb = 0; kb < 4; ++kb) {
            const int co = h * 128 + kb * 32;
            __syncthreads();
            cp16(&As[ar0 * 32 + ak0], Ab + (long)ar0 * 1024 + co + ak0);
            cp16(&As[ar1 * 32 + ak1], Ab + (long)ar1 * 1024 + co + ak1);
            cp16(&Bs[ar0 * 32 + ak0], Bb + (long)ar0 * 1024 + co + ak0);
            cp16(&Bs[ar1 * 32 + ak1], Bb + (long)ar1 * 1024 + co + ak1);
            __syncthreads();

            bf16x8 af[4], bfr[4];
#pragma unroll
            for (int i = 0; i < 4; ++i)
                af[i] = *(const bf16x8*)&As[(wm + i * 16 + v) * 32 + u * 8];
#pragma unroll
            for (int j = 0; j < 4; ++j)
                bfr[j] = *(const bf16x8*)&Bs[(wn + j * 16 + v) * 32 + u * 8];
#pragma unroll
            for (int i = 0; i < 4; ++i)
#pragma unroll
                for (int j = 0; j < 4; ++j)
                    acc[i][j] = mfma16(af[i], bfr[j], acc[i][j]);
        }
        // epilogue for head h: exp, accumulate den, store bf16x4 along k
        __bf16* Ph = P + ((long)(bloc * 8 + h) * Cq + q0l) * 2048 + k0;
#pragma unroll
        for (int i = 0; i < 4; ++i) {
#pragma unroll
            for (int j = 0; j < 4; ++j) {
                const int kc = wm + i * 16 + u * 4;       // key (tile-local)
                const int qr = wn + j * 16 + v;           // query (tile-local)
                bf16x4 pk;
#pragma unroll
                for (int r = 0; r < 4; ++r) {
                    float e = __expf(acc[i][j][r]);
                    den[i][j][r] += e;
                    pk[r] = (__bf16)e;
                }
                *(bf16x4*)&Ph[(long)qr * 2048 + kc] = pk;
            }
        }
    }

    // normalize the 8 tiles in place (own stores, same lane)
#pragma unroll
    for (int i = 0; i < 4; ++i)
#pragma unroll
        for (int j = 0; j < 4; ++j) {
            f32x4 rv;
#pragma unroll
            for (int r = 0; r < 4; ++r) rv[r] = 1.0f / den[i][j][r];
            den[i][j] = rv;
        }
    __threadfence();
#pragma unroll 1
    for (int h = 0; h < 8; ++h) {
        __bf16* Ph = P + ((long)(bloc * 8 + h) * Cq + q0l) * 2048 + k0;
#pragma unroll
        for (int i = 0; i < 4; ++i) {
#pragma unroll
            for (int j = 0; j < 4; ++j) {
                const int kc = wm + i * 16 + u * 4;
                const int qr = wn + j * 16 + v;
                bf16x4 t = *(bf16x4*)&Ph[(long)qr * 2048 + kc];
#pragma unroll
                for (int r = 0; r < 4; ++r)
                    t[r] = (__bf16)((float)t[r] * den[i][j][r]);
                *(bf16x4*)&Ph[(long)qr * 2048 + kc] = t;
            }
        }
    }
}

// ---------------------------------------------------------------------------
// ctxT[dh][q] = sum_k vt[b,h,dh,k] * P[bloc,h,q,k]  (Kdim=2048, 64 BK-iters)
// Chunked to match qk_head_softmax: grid.y = nb*8 (bloc,h), grid.x = C/128.
// A = vt rows (dh, stride 2048), Bt = P rows (q, stride 2048).
// Epilogue stores ctx in concat layout [b][q][h*128+dh] via bf16x4.
__global__ __launch_bounds__(256, 2) void pv_gemm(
    const __bf16* __restrict__ vt, const __bf16* __restrict__ P,
    __bf16* __restrict__ ctx, int b_base, int q_base)
{
    __shared__ __bf16 As[128 * 32];
    __shared__ __bf16 Bs[128 * 32];
    const int tid  = threadIdx.x;
    const int lane = tid & 63;
    const int u = lane >> 4, v = lane & 15;
    const int w = tid >> 6;
    const int wm = (w >> 1) * 64, wn = (w & 1) * 64;
    const int bhl  = blockIdx.y;                  // bloc*8 + h
    const int bloc = bhl >> 3, h = bhl & 7;
    const int b    = b_base + bloc;
    const int q0l  = blockIdx.x * 128;
    const int q0g  = q_base + q0l;
    const long Cq  = (long)gridDim.x * 128;

    const int c0 = tid, c1 = tid + 256;
    const int ar0 = c0 >> 2, ak0 = (c0 & 3) * 8;
    const int ar1 = c1 >> 2, ak1 = (c1 & 3) * 8;

    const __bf16* Ab = vt + (long)(b * 8 + h) * 128 * 2048;
    const __bf16* Bb = P  + ((long)(bloc * 8 + h) * Cq + q0l) * 2048;

    f32x4 acc[4][4];
#pragma unroll
    for (int i = 0; i < 4; ++i)
#pragma unroll
        for (int j = 0; j < 4; ++j) acc[i][j] = (f32x4){0.f, 0.f, 0.f, 0.f};

    for (int k0 = 0; k0 < 2048; k0 += 32) {
        __syncthreads();
        cp16(&As[ar0 * 32 + ak0], Ab + (long)ar0 * 2048 + k0 + ak0);
        cp16(&As[ar1 * 32 + ak1], Ab + (long)ar1 * 2048 + k0 + ak1);
        cp16(&Bs[ar0 * 32 + ak0], Bb + (long)ar0 * 2048 + k0 + ak0);
        cp16(&Bs[ar1 * 32 + ak1], Bb + (long)ar1 * 2048 + k0 + ak1);
        __syncthreads();

        bf16x8 af[4], bfr[4];
#pragma unroll
        for (int i = 0; i < 4; ++i)
            af[i] = *(const bf16x8*)&As[(wm + i * 16 + v) * 32 + u * 8];
#pragma unroll
        for (int j = 0; j < 4; ++j)
            bfr[j] = *(const bf16x8*)&Bs[(wn + j * 16 + v) * 32 + u * 8];
#pragma unroll
        for (int i = 0; i < 4; ++i)
#pragma unroll
            for (int j = 0; j < 4; ++j)
                acc[i][j] = mfma16(af[i], bfr[j], acc[i][j]);
    }

#pragma unroll
    for (int i = 0; i < 4; ++i) {
#pragma unroll
        for (int j = 0; j < 4; ++j) {
            const int dh0 = wm + i * 16 + u * 4;          // 4-consec feature
            const int q   = q0g + wn + j * 16 + v;
            bf16x4 pk;
#pragma unroll
            for (int r = 0; r < 4; ++r) pk[r] = (__bf16)acc[i][j][r];
            *(bf16x4*)&ctx[((long)b * 2048 + q) * 1024 + h * 128 + dh0] = pk;
        }
    }
}

// ---------------------------------------------------------------------------
// Fallback (round-1 fused attention) if ws can't hold even the smallest P.
__global__ __launch_bounds__(256, 2) void attn_softmax_head(
    const __bf16* __restrict__ qp, const __bf16* __restrict__ kp,
    const __bf16* __restrict__ vt, __bf16* __restrict__ ctx)
{
    __shared__ float part[8 * 256];
    __shared__ float pb[4][2][16 * 33];

    const int tid  = threadIdx.x;
    const int lane = tid & 63;
    const int w = tid >> 6;
    const int u = lane >> 4, v = lane & 15;
    const int b  = blockIdx.y;
    const int q0 = blockIdx.x * 16;

    const long qoff = ((long)b * 2048 + q0 + v) * 1024;
    bf16x8 qf[2][4];
#pragma unroll
    for (int hh = 0; hh < 2; ++hh) {
        const int h = 2 * w + hh;
#pragma unroll
        for (int kk = 0; kk < 4; ++kk)
            qf[hh][kk] = *(const bf16x8*)(qp + qoff + h * 128 + kk * 32 + u * 8);
    }

    f32x4 acc[2][8];
#pragma unroll
    for (int hh = 0; hh < 2; ++hh)
#pragma unroll
        for (int dt = 0; dt < 8; ++dt) acc[hh][dt] = (f32x4){0.f, 0.f, 0.f, 0.f};

    for (int kt = 0; kt < 2048; kt += 32) {
        float e[2][2][4];
#pragma unroll
        for (int hh = 0; hh < 2; ++hh) {
            const int h = 2 * w + hh;
#pragma unroll
            for (int t = 0; t < 2; ++t) {
                f32x4 s = (f32x4){0.f, 0.f, 0.f, 0.f};
                const __bf16* kb = kp + ((long)b * 2048 + kt + t * 16 + v) * 1024
                                      + h * 128 + u * 8;
#pragma unroll
                for (int kk = 0; kk < 4; ++kk)
                    s = mfma16(*(const bf16x8*)(kb + kk * 32), qf[hh][kk], s);
#pragma unroll
                for (int r = 0; r < 4; ++r) e[hh][t][r] = __expf(s[r]);
            }
        }
#pragma unroll
        for (int t = 0; t < 2; ++t)
#pragma unroll
            for (int r = 0; r < 4; ++r)
                part[(t * 4 + r) * 256 + w * 64 + lane] = e[0][t][r] + e[1][t][r];
        __syncthreads();
#pragma unroll
        for (int t = 0; t < 2; ++t)
#pragma unroll
            for (int r = 0; r < 4; ++r) {
                const int j = (t * 4 + r) * 256 + lane;
                const float den = part[j] + part[j + 64] + part[j + 128] + part[j + 192];
                const float rinv = 1.0f / den;
                const int kl = t * 16 + u * 4 + r;
                pb[w][0][v * 33 + kl] = e[0][t][r] * rinv;
                pb[w][1][v * 33 + kl] = e[1][t][r] * rinv;
            }
        bf16x8 pf[2];
#pragma unroll
        for (int hh = 0; hh < 2; ++hh)
#pragma unroll
            for (int jj = 0; jj < 8; ++jj)
                pf[hh][jj] = (__bf16)pb[w][hh][v * 33 + u * 8 + jj];
#pragma unroll
        for (int hh = 0; hh < 2; ++hh) {
            const int h = 2 * w + hh;
            const __bf16* vb = vt + ((long)(b * 8 + h) * 128 + v) * 2048 + kt + u * 8;
#pragma unroll
            for (int dt = 0; dt < 8; ++dt)
                acc[hh][dt] = mfma16(*(const bf16x8*)(vb + (long)dt * 16 * 2048),
                                     pf[hh], acc[hh][dt]);
        }
        __syncthreads();
    }

#pragma unroll
    for (int hh = 0; hh < 2; ++hh) {
        const int h = 2 * w + hh;
#pragma unroll
        for (int dt = 0; dt < 8; ++dt) {
            bf16x4 o;
#pragma unroll
            for (int r = 0; r < 4; ++r) o[r] = (__bf16)acc[hh][dt][r];
            *(bf16x4*)(ctx + ((long)b * 2048 + q0 + v) * 1024
                           + h * 128 + dt * 16 + u * 4) = o;
        }
    }
}

// ---------------------------------------------------------------------------
extern "C" void kernel_launch(void* const* d_in, const int* in_sizes, int n_in,
                              void* d_out, int out_size, void* d_ws, size_t ws_size,
                              hipStream_t stream)
{
    const float* Q  = (const float*)d_in[0];
    const float* K  = (const float*)d_in[1];
    const float* V  = (const float*)d_in[2];
    const float* WQ = (const float*)d_in[3];
    const float* WK = (const float*)d_in[4];
    const float* WV = (const float*)d_in[5];
    const float* WO = (const float*)d_in[6];

    // workspace layout (bf16 elems):
    //   4x 1M weights (8.4 MB) + 4x 8.4M tensors (67.1 MB) + adaptive P
    __bf16* ws = (__bf16*)d_ws;
    __bf16* wq = ws;
    __bf16* wk = wq + 1048576;
    __bf16* wv = wk + 1048576;
    __bf16* wo = wv + 1048576;
    __bf16* xb = wo + 1048576;     // cast buffer; reused as ctx
    __bf16* qp = xb + 8388608;
    __bf16* kp = qp + 8388608;
    __bf16* vt = kp + 8388608;
    __bf16* pbuf = vt + 8388608;   // P chunk buffer (size from ladder)

    const float qscale = 0.08838834764831845f;   // 1/sqrt(128)

    cast_f32_to_bf16<<<1024, 256, 0, stream>>>(WQ, wq, 262144);
    cast_f32_to_bf16<<<1024, 256, 0, stream>>>(WK, wk, 262144);
    cast_f32_to_bf16<<<1024, 256, 0, stream>>>(WV, wv, 262144);
    cast_f32_to_bf16<<<1024, 256, 0, stream>>>(WO, wo, 262144);

    dim3 gg(8, 64), gb(256);
    cast_f32_to_bf16<<<4096, 256, 0, stream>>>(Q, xb, 2097152);
    gemm_bt<0><<<gg, gb, 0, stream>>>(xb, wq, qp, qscale);
    cast_f32_to_bf16<<<4096, 256, 0, stream>>>(K, xb, 2097152);
    gemm_bt<0><<<gg, gb, 0, stream>>>(xb, wk, kp, 1.0f);
    cast_f32_to_bf16<<<4096, 256, 0, stream>>>(V, xb, 2097152);
    gemm_bt<2><<<gg, gb, 0, stream>>>(xb, wv, vt, 1.0f);

    // adaptive P sizing: (nb batches) x 8h x (C queries) x 2048 keys, bf16
    const size_t baseBytes = 37748736ULL * 2ULL;          // 75.5 MB
    const size_t avail = (ws_size > baseBytes) ? ws_size - baseBytes : 0;
    const int cfgs[6][2] = {{4,2048},{2,2048},{1,2048},{1,1024},{1,512},{1,256}};
    int nb = 0, C = 0;
    for (int c = 0; c < 6; ++c) {
        const size_t need = (size_t)cfgs[c][0] * 8 * cfgs[c][1] * 2048 * 2;
        if (need <= avail) { nb = cfgs[c][0]; C = cfgs[c][1]; break; }
    }

    if (nb) {
        for (int bb = 0; bb < 4; bb += nb)
            for (int qq = 0; qq < 2048; qq += C) {
                qk_head_softmax<<<dim3(16, C / 128, nb), gb, 0, stream>>>(
                    kp, qp, pbuf, bb, qq);
                pv_gemm<<<dim3(C / 128, nb * 8), gb, 0, stream>>>(
                    vt, pbuf, xb, bb, qq);
            }
    } else {
        attn_softmax_head<<<dim3(128, 4), gb, 0, stream>>>(qp, kp, vt, xb);
    }

    gemm_bt<1><<<gg, gb, 0, stream>>>(xb, wo, (float*)d_out, 1.0f);
}

// Round 4
// 578.632 us; speedup vs baseline: 1.4880x; 1.2719x over previous
//
#include <hip/hip_runtime.h>
#include <math.h>
#include <stdint.h>

// ---------------------------------------------------------------------------
// MultiHeadAttention, softmax over HEAD axis (dim=1), bf16 MFMA pipeline.
// B=4, S=2048, DIM=1024, H=8, DH=128.
//   q = (Q WQ^T) * 1/sqrt(128)   [b,s,1024] bf16 (scale folded in epilogue)
//   k =  K WK^T                  [b,s,1024] bf16
//   vt = (V WV^T) transposed ->  [b,h,dh,s] bf16 (epilogue transpose)
//   P[bloc,h,q,k] = exp(sT)/sum_h exp  via qk_head_softmax v2:
//     64k x 128q tile; e for all 8 heads kept in REGISTERS (bf16), den in
//     registers; single normalized P write via LDS-transpose (coalesced rows).
//   ctx = P·V via pv_gemm (pure GEMM), out = ctx WO^T fp32 -> d_out
// ---------------------------------------------------------------------------

typedef __attribute__((ext_vector_type(8))) __bf16 bf16x8;
typedef __attribute__((ext_vector_type(4))) __bf16 bf16x4;
typedef __attribute__((ext_vector_type(4))) float  f32x4;

__device__ __forceinline__ f32x4 mfma16(bf16x8 a, bf16x8 b, f32x4 c) {
    return __builtin_amdgcn_mfma_f32_16x16x32_bf16(a, b, c, 0, 0, 0);
}

// async global->LDS, 16B per lane; LDS dest must be wave-uniform-base + lane*16
__device__ __forceinline__ void cp16(void* lds, const void* g) {
    __builtin_amdgcn_global_load_lds(
        (__attribute__((address_space(1))) void*)(void*)(const_cast<void*>(g)),
        (__attribute__((address_space(3))) void*)lds,
        16, 0, 0);
}

// ---------------------------------------------------------------------------
__global__ void cast_f32_to_bf16(const float* __restrict__ src,
                                 __bf16* __restrict__ dst, int n4) {
    int i = blockIdx.x * blockDim.x + threadIdx.x;
    const int stride = gridDim.x * blockDim.x;
    for (; i < n4; i += stride) {
        float4 f = ((const float4*)src)[i];
        bf16x4 o;
        o[0] = (__bf16)f.x; o[1] = (__bf16)f.y; o[2] = (__bf16)f.z; o[3] = (__bf16)f.w;
        ((bf16x4*)dst)[i] = o;
    }
}

// 4 weight tensors in one launch (saves 3 launch overheads)
__global__ void cast4_f32_to_bf16(const float* __restrict__ s0, __bf16* __restrict__ d0,
                                  const float* __restrict__ s1, __bf16* __restrict__ d1,
                                  const float* __restrict__ s2, __bf16* __restrict__ d2,
                                  const float* __restrict__ s3, __bf16* __restrict__ d3,
                                  int n4) {
    const float* s = (blockIdx.y == 0) ? s0 : (blockIdx.y == 1) ? s1
                    : (blockIdx.y == 2) ? s2 : s3;
    __bf16* d = (blockIdx.y == 0) ? d0 : (blockIdx.y == 1) ? d1
               : (blockIdx.y == 2) ? d2 : d3;
    int i = blockIdx.x * blockDim.x + threadIdx.x;
    const int stride = gridDim.x * blockDim.x;
    for (; i < n4; i += stride) {
        float4 f = ((const float4*)s)[i];
        bf16x4 o;
        o[0] = (__bf16)f.x; o[1] = (__bf16)f.y; o[2] = (__bf16)f.z; o[3] = (__bf16)f.w;
        ((bf16x4*)d)[i] = o;
    }
}

// ---------------------------------------------------------------------------
// C[8192,1024] = A[8192,1024] * Bt[1024,1024]^T   (Bt stored [N,K] row-major)
// MODE 0: bf16 out, natural [m,n], * scale
// MODE 1: f32 out, natural [m,n]
// MODE 2: bf16 out, v-transpose: out[((b*8+h)*128+dh)*2048 + s]
template<int MODE>
__global__ __launch_bounds__(256, 2) void gemm_bt(const __bf16* __restrict__ A,
                                                  const __bf16* __restrict__ Bt,
                                                  void* __restrict__ out,
                                                  float scale)
{
    __shared__ __bf16 As[128 * 32];
    __shared__ __bf16 Bs[128 * 32];
    const int tid  = threadIdx.x;
    const int lane = tid & 63;
    const int u = lane >> 4, v = lane & 15;   // quad, col-in-tile
    const int w = tid >> 6;
    const int wm = (w >> 1) * 64, wn = (w & 1) * 64;
    const long tM = (long)blockIdx.y * 128;
    const int  tN = blockIdx.x * 128;

    f32x4 acc[4][4];
#pragma unroll
    for (int i = 0; i < 4; ++i)
#pragma unroll
        for (int j = 0; j < 4; ++j) acc[i][j] = (f32x4){0.f, 0.f, 0.f, 0.f};

    const int c0 = tid, c1 = tid + 256;
    const int ar0 = c0 >> 2, ak0 = (c0 & 3) * 8;
    const int ar1 = c1 >> 2, ak1 = (c1 & 3) * 8;

    const __bf16* Ab = A  + tM * 1024;
    const __bf16* Bb = Bt + (long)tN * 1024;

    for (int k0 = 0; k0 < 1024; k0 += 32) {
        __syncthreads();
        cp16(&As[ar0 * 32 + ak0], Ab + (long)ar0 * 1024 + k0 + ak0);
        cp16(&As[ar1 * 32 + ak1], Ab + (long)ar1 * 1024 + k0 + ak1);
        cp16(&Bs[ar0 * 32 + ak0], Bb + (long)ar0 * 1024 + k0 + ak0);
        cp16(&Bs[ar1 * 32 + ak1], Bb + (long)ar1 * 1024 + k0 + ak1);
        __syncthreads();

        bf16x8 af[4], bfr[4];
#pragma unroll
        for (int i = 0; i < 4; ++i)
            af[i] = *(const bf16x8*)&As[(wm + i * 16 + v) * 32 + u * 8];
#pragma unroll
        for (int j = 0; j < 4; ++j)
            bfr[j] = *(const bf16x8*)&Bs[(wn + j * 16 + v) * 32 + u * 8];
#pragma unroll
        for (int i = 0; i < 4; ++i)
#pragma unroll
            for (int j = 0; j < 4; ++j)
                acc[i][j] = mfma16(af[i], bfr[j], acc[i][j]);
    }

#pragma unroll
    for (int i = 0; i < 4; ++i) {
#pragma unroll
        for (int j = 0; j < 4; ++j) {
            const long row0 = tM + wm + i * 16 + u * 4;      // + r
            const int  col  = tN + wn + j * 16 + v;
            if (MODE == 0) {
                __bf16* o = (__bf16*)out;
#pragma unroll
                for (int r = 0; r < 4; ++r)
                    o[(row0 + r) * 1024 + col] = (__bf16)(acc[i][j][r] * scale);
            } else if (MODE == 1) {
                float* o = (float*)out;
#pragma unroll
                for (int r = 0; r < 4; ++r)
                    o[(row0 + r) * 1024 + col] = acc[i][j][r];
            } else {
                __bf16* o = (__bf16*)out;
                const int bidx = (int)(row0 >> 11);
                const int s    = (int)(row0 & 2047);          // 4-aligned
                const int h = col >> 7, dh = col & 127;
                bf16x4 pk;
#pragma unroll
                for (int r = 0; r < 4; ++r) pk[r] = (__bf16)acc[i][j][r];
                *(bf16x4*)&o[((long)(bidx * 8 + h) * 128 + dh) * 2048 + s] = pk;
            }
        }
    }
}

// ---------------------------------------------------------------------------
// qk_head_softmax v2: one (b, 64k x 128q) tile, all 8 heads.
// Per head: sT[k][q] GEMM slice (Kdim=128, 4 BK-iters); e=exp kept bf16 in
// REGISTERS across heads (e8[8][2][4] bf16x4 = 128 VGPR); den accumulates
// in f32 registers at fixed (k,q) positions. After 8 heads: normalize in
// registers, write each head's P tile through an LDS transpose buffer so
// global stores are contiguous 128B row-chunks of P[bloc][h][q][k].
// Numerics identical to the verified round-3 path.
struct QkSm {
    union {
        struct { __bf16 As[64 * 32]; __bf16 Bs[128 * 32]; } s;   // 12 KB
        __bf16 tb[128 * 68];                                      // 17 KB
    };
};
__global__ __launch_bounds__(256, 2) void qk_head_softmax(
    const __bf16* __restrict__ kp, const __bf16* __restrict__ qp,
    __bf16* __restrict__ P, int b_base, int q_base)
{
    __shared__ QkSm sm;
    const int tid  = threadIdx.x;
    const int lane = tid & 63;
    const int u = lane >> 4, v = lane & 15;
    const int w = tid >> 6;
    const int wm = (w >> 1) * 32, wn = (w & 1) * 64;   // 2x2 waves over 64k x 128q
    const int bloc = blockIdx.z;
    const int b    = b_base + bloc;
    const int k0   = blockIdx.x * 64;             // M-tile = 64 keys
    const int q0l  = blockIdx.y * 128;            // N-tile = 128 queries (local)
    const int q0g  = q_base + q0l;
    const long Cq  = (long)gridDim.y * 128;

    // staging: As 64x32 (1 chunk/thread), Bs 128x32 (2 chunks/thread)
    const int ar0 = tid >> 2, ak0 = (tid & 3) * 8;
    const int ar1 = ar0 + 64, ak1 = ak0;

    const __bf16* Ka = kp + ((long)b * 2048 + k0) * 1024;
    const __bf16* Qa = qp + ((long)b * 2048 + q0g) * 1024;

    f32x4 den[2][4];
#pragma unroll
    for (int i = 0; i < 2; ++i)
#pragma unroll
        for (int j = 0; j < 4; ++j) den[i][j] = (f32x4){0.f, 0.f, 0.f, 0.f};

    bf16x4 e8[8][2][4];

#pragma unroll
    for (int h = 0; h < 8; ++h) {
        f32x4 acc[2][4];
#pragma unroll
        for (int i = 0; i < 2; ++i)
#pragma unroll
            for (int j = 0; j < 4; ++j) acc[i][j] = (f32x4){0.f, 0.f, 0.f, 0.f};

#pragma unroll
        for (int kb = 0; kb < 4; ++kb) {
            const int co = h * 128 + kb * 32;
            __syncthreads();
            cp16(&sm.s.As[ar0 * 32 + ak0], Ka + (long)ar0 * 1024 + co + ak0);
            cp16(&sm.s.Bs[ar0 * 32 + ak0], Qa + (long)ar0 * 1024 + co + ak0);
            cp16(&sm.s.Bs[ar1 * 32 + ak1], Qa + (long)ar1 * 1024 + co + ak1);
            __syncthreads();

            bf16x8 af[2], bfr[4];
#pragma unroll
            for (int i = 0; i < 2; ++i)
                af[i] = *(const bf16x8*)&sm.s.As[(wm + i * 16 + v) * 32 + u * 8];
#pragma unroll
            for (int j = 0; j < 4; ++j)
                bfr[j] = *(const bf16x8*)&sm.s.Bs[(wn + j * 16 + v) * 32 + u * 8];
#pragma unroll
            for (int i = 0; i < 2; ++i)
#pragma unroll
                for (int j = 0; j < 4; ++j)
                    acc[i][j] = mfma16(af[i], bfr[j], acc[i][j]);
        }
        // epilogue for head h: e = exp(acc) -> registers; den += e
#pragma unroll
        for (int i = 0; i < 2; ++i)
#pragma unroll
            for (int j = 0; j < 4; ++j) {
                bf16x4 pk;
#pragma unroll
                for (int r = 0; r < 4; ++r) {
                    float e = __expf(acc[i][j][r]);
                    den[i][j][r] += e;
                    pk[r] = (__bf16)e;
                }
                e8[h][i][j] = pk;
            }
    }

    // normalize + store each head's tile via LDS transpose (coalesced rows)
    f32x4 rinv[2][4];
#pragma unroll
    for (int i = 0; i < 2; ++i)
#pragma unroll
        for (int j = 0; j < 4; ++j)
#pragma unroll
            for (int r = 0; r < 4; ++r) rinv[i][j][r] = 1.0f / den[i][j][r];

#pragma unroll
    for (int h = 0; h < 8; ++h) {
        __syncthreads();   // prior tb reads (or final MFMA ds_reads) complete
#pragma unroll
        for (int i = 0; i < 2; ++i)
#pragma unroll
            for (int j = 0; j < 4; ++j) {
                const int kc = wm + i * 16 + u * 4;   // key (tile-local, 0..63)
                const int qr = wn + j * 16 + v;       // query (tile-local)
                bf16x4 t = e8[h][i][j];
                bf16x4 o;
#pragma unroll
                for (int r = 0; r < 4; ++r)
                    o[r] = (__bf16)((float)t[r] * rinv[i][j][r]);
                *(bf16x4*)&sm.tb[qr * 68 + kc] = o;
            }
        __syncthreads();
        __bf16* Ph = P + ((long)(bloc * 8 + h) * Cq + q0l) * 2048 + k0;
#pragma unroll
        for (int p = 0; p < 4; ++p) {
            const int qq = p * 32 + (tid >> 3);       // 32 q-rows per pass
            const int kk = (tid & 7) * 8;             // 8 lanes x 16B = 128B row
            *(bf16x8*)&Ph[(long)qq * 2048 + kk] = *(const bf16x8*)&sm.tb[qq * 68 + kk];
        }
    }
}

// ---------------------------------------------------------------------------
// ctxT[dh][q] = sum_k vt[b,h,dh,k] * P[bloc,h,q,k]  (Kdim=2048, 64 BK-iters)
// A = vt rows (dh, stride 2048), Bt = P rows (q, stride 2048).
// Epilogue stores ctx in concat layout [b][q][h*128+dh] via bf16x4.
__global__ __launch_bounds__(256, 2) void pv_gemm(
    const __bf16* __restrict__ vt, const __bf16* __restrict__ P,
    __bf16* __restrict__ ctx, int b_base, int q_base)
{
    __shared__ __bf16 As[128 * 32];
    __shared__ __bf16 Bs[128 * 32];
    const int tid  = threadIdx.x;
    const int lane = tid & 63;
    const int u = lane >> 4, v = lane & 15;
    const int w = tid >> 6;
    const int wm = (w >> 1) * 64, wn = (w & 1) * 64;
    const int bhl  = blockIdx.y;                  // bloc*8 + h
    const int bloc = bhl >> 3, h = bhl & 7;
    const int b    = b_base + bloc;
    const int q0l  = blockIdx.x * 128;
    const int q0g  = q_base + q0l;
    const long Cq  = (long)gridDim.x * 128;

    const int c0 = tid, c1 = tid + 256;
    const int ar0 = c0 >> 2, ak0 = (c0 & 3) * 8;
    const int ar1 = c1 >> 2, ak1 = (c1 & 3) * 8;

    const __bf16* Ab = vt + (long)(b * 8 + h) * 128 * 2048;
    const __bf16* Bb = P  + ((long)(bloc * 8 + h) * Cq + q0l) * 2048;

    f32x4 acc[4][4];
#pragma unroll
    for (int i = 0; i < 4; ++i)
#pragma unroll
        for (int j = 0; j < 4; ++j) acc[i][j] = (f32x4){0.f, 0.f, 0.f, 0.f};

    for (int k0 = 0; k0 < 2048; k0 += 32) {
        __syncthreads();
        cp16(&As[ar0 * 32 + ak0], Ab + (long)ar0 * 2048 + k0 + ak0);
        cp16(&As[ar1 * 32 + ak1], Ab + (long)ar1 * 2048 + k0 + ak1);
        cp16(&Bs[ar0 * 32 + ak0], Bb + (long)ar0 * 2048 + k0 + ak0);
        cp16(&Bs[ar1 * 32 + ak1], Bb + (long)ar1 * 2048 + k0 + ak1);
        __syncthreads();

        bf16x8 af[4], bfr[4];
#pragma unroll
        for (int i = 0; i < 4; ++i)
            af[i] = *(const bf16x8*)&As[(wm + i * 16 + v) * 32 + u * 8];
#pragma unroll
        for (int j = 0; j < 4; ++j)
            bfr[j] = *(const bf16x8*)&Bs[(wn + j * 16 + v) * 32 + u * 8];
#pragma unroll
        for (int i = 0; i < 4; ++i)
#pragma unroll
            for (int j = 0; j < 4; ++j)
                acc[i][j] = mfma16(af[i], bfr[j], acc[i][j]);
    }

#pragma unroll
    for (int i = 0; i < 4; ++i) {
#pragma unroll
        for (int j = 0; j < 4; ++j) {
            const int dh0 = wm + i * 16 + u * 4;          // 4-consec feature
            const int q   = q0g + wn + j * 16 + v;
            bf16x4 pk;
#pragma unroll
            for (int r = 0; r < 4; ++r) pk[r] = (__bf16)acc[i][j][r];
            *(bf16x4*)&ctx[((long)b * 2048 + q) * 1024 + h * 128 + dh0] = pk;
        }
    }
}

// ---------------------------------------------------------------------------
// Fallback (round-1 fused attention) if ws can't hold even the smallest P.
__global__ __launch_bounds__(256, 2) void attn_softmax_head(
    const __bf16* __restrict__ qp, const __bf16* __restrict__ kp,
    const __bf16* __restrict__ vt, __bf16* __restrict__ ctx)
{
    __shared__ float part[8 * 256];
    __shared__ float pb[4][2][16 * 33];

    const int tid  = threadIdx.x;
    const int lane = tid & 63;
    const int w = tid >> 6;
    const int u = lane >> 4, v = lane & 15;
    const int b  = blockIdx.y;
    const int q0 = blockIdx.x * 16;

    const long qoff = ((long)b * 2048 + q0 + v) * 1024;
    bf16x8 qf[2][4];
#pragma unroll
    for (int hh = 0; hh < 2; ++hh) {
        const int h = 2 * w + hh;
#pragma unroll
        for (int kk = 0; kk < 4; ++kk)
            qf[hh][kk] = *(const bf16x8*)(qp + qoff + h * 128 + kk * 32 + u * 8);
    }

    f32x4 acc[2][8];
#pragma unroll
    for (int hh = 0; hh < 2; ++hh)
#pragma unroll
        for (int dt = 0; dt < 8; ++dt) acc[hh][dt] = (f32x4){0.f, 0.f, 0.f, 0.f};

    for (int kt = 0; kt < 2048; kt += 32) {
        float e[2][2][4];
#pragma unroll
        for (int hh = 0; hh < 2; ++hh) {
            const int h = 2 * w + hh;
#pragma unroll
            for (int t = 0; t < 2; ++t) {
                f32x4 s = (f32x4){0.f, 0.f, 0.f, 0.f};
                const __bf16* kb = kp + ((long)b * 2048 + kt + t * 16 + v) * 1024
                                      + h * 128 + u * 8;
#pragma unroll
                for (int kk = 0; kk < 4; ++kk)
                    s = mfma16(*(const bf16x8*)(kb + kk * 32), qf[hh][kk], s);
#pragma unroll
                for (int r = 0; r < 4; ++r) e[hh][t][r] = __expf(s[r]);
            }
        }
#pragma unroll
        for (int t = 0; t < 2; ++t)
#pragma unroll
            for (int r = 0; r < 4; ++r)
                part[(t * 4 + r) * 256 + w * 64 + lane] = e[0][t][r] + e[1][t][r];
        __syncthreads();
#pragma unroll
        for (int t = 0; t < 2; ++t)
#pragma unroll
            for (int r = 0; r < 4; ++r) {
                const int j = (t * 4 + r) * 256 + lane;
                const float den = part[j] + part[j + 64] + part[j + 128] + part[j + 192];
                const float rinv = 1.0f / den;
                const int kl = t * 16 + u * 4 + r;
                pb[w][0][v * 33 + kl] = e[0][t][r] * rinv;
                pb[w][1][v * 33 + kl] = e[1][t][r] * rinv;
            }
        bf16x8 pf[2];
#pragma unroll
        for (int hh = 0; hh < 2; ++hh)
#pragma unroll
            for (int jj = 0; jj < 8; ++jj)
                pf[hh][jj] = (__bf16)pb[w][hh][v * 33 + u * 8 + jj];
#pragma unroll
        for (int hh = 0; hh < 2; ++hh) {
            const int h = 2 * w + hh;
            const __bf16* vb = vt + ((long)(b * 8 + h) * 128 + v) * 2048 + kt + u * 8;
#pragma unroll
            for (int dt = 0; dt < 8; ++dt)
                acc[hh][dt] = mfma16(*(const bf16x8*)(vb + (long)dt * 16 * 2048),
                                     pf[hh], acc[hh][dt]);
        }
        __syncthreads();
    }

#pragma unroll
    for (int hh = 0; hh < 2; ++hh) {
        const int h = 2 * w + hh;
#pragma unroll
        for (int dt = 0; dt < 8; ++dt) {
            bf16x4 o;
#pragma unroll
            for (int r = 0; r < 4; ++r) o[r] = (__bf16)acc[hh][dt][r];
            *(bf16x4*)(ctx + ((long)b * 2048 + q0 + v) * 1024
                           + h * 128 + dt * 16 + u * 4) = o;
        }
    }
}

// ---------------------------------------------------------------------------
extern "C" void kernel_launch(void* const* d_in, const int* in_sizes, int n_in,
                              void* d_out, int out_size, void* d_ws, size_t ws_size,
                              hipStream_t stream)
{
    const float* Q  = (const float*)d_in[0];
    const float* K  = (const float*)d_in[1];
    const float* V  = (const float*)d_in[2];
    const float* WQ = (const float*)d_in[3];
    const float* WK = (const float*)d_in[4];
    const float* WV = (const float*)d_in[5];
    const float* WO = (const float*)d_in[6];

    // workspace layout (bf16 elems):
    //   4x 1M weights (8.4 MB) + 4x 8.4M tensors (67.1 MB) + adaptive P
    __bf16* ws = (__bf16*)d_ws;
    __bf16* wq = ws;
    __bf16* wk = wq + 1048576;
    __bf16* wv = wk + 1048576;
    __bf16* wo = wv + 1048576;
    __bf16* xb = wo + 1048576;     // cast buffer; reused as ctx
    __bf16* qp = xb + 8388608;
    __bf16* kp = qp + 8388608;
    __bf16* vt = kp + 8388608;
    __bf16* pbuf = vt + 8388608;   // P chunk buffer (size from ladder)

    const float qscale = 0.08838834764831845f;   // 1/sqrt(128)

    cast4_f32_to_bf16<<<dim3(256, 4), 256, 0, stream>>>(
        WQ, wq, WK, wk, WV, wv, WO, wo, 262144);

    dim3 gg(8, 64), gb(256);
    cast_f32_to_bf16<<<4096, 256, 0, stream>>>(Q, xb, 2097152);
    gemm_bt<0><<<gg, gb, 0, stream>>>(xb, wq, qp, qscale);
    cast_f32_to_bf16<<<4096, 256, 0, stream>>>(K, xb, 2097152);
    gemm_bt<0><<<gg, gb, 0, stream>>>(xb, wk, kp, 1.0f);
    cast_f32_to_bf16<<<4096, 256, 0, stream>>>(V, xb, 2097152);
    gemm_bt<2><<<gg, gb, 0, stream>>>(xb, wv, vt, 1.0f);

    // adaptive P sizing: (nb batches) x 8h x (C queries) x 2048 keys, bf16
    const size_t baseBytes = 37748736ULL * 2ULL;          // 75.5 MB
    const size_t avail = (ws_size > baseBytes) ? ws_size - baseBytes : 0;
    const int cfgs[6][2] = {{4,2048},{2,2048},{1,2048},{1,1024},{1,512},{1,256}};
    int nb = 0, C = 0;
    for (int c = 0; c < 6; ++c) {
        const size_t need = (size_t)cfgs[c][0] * 8 * cfgs[c][1] * 2048 * 2;
        if (need <= avail) { nb = cfgs[c][0]; C = cfgs[c][1]; break; }
    }

    if (nb) {
        for (int bb = 0; bb < 4; bb += nb)
            for (int qq = 0; qq < 2048; qq += C) {
                qk_head_softmax<<<dim3(32, C / 128, nb), gb, 0, stream>>>(
                    kp, qp, pbuf, bb, qq);
                pv_gemm<<<dim3(C / 128, nb * 8), gb, 0, stream>>>(
                    vt, pbuf, xb, bb, qq);
            }
    } else {
        attn_softmax_head<<<dim3(128, 4), gb, 0, stream>>>(qp, kp, vt, xb);
    }

    gemm_bt<1><<<gg, gb, 0, stream>>>(xb, wo, (float*)d_out, 1.0f);
}

// Round 5
// 505.619 us; speedup vs baseline: 1.7028x; 1.1444x over previous
//
#include <hip/hip_runtime.h>
#include <math.h>
#include <stdint.h>

// ---------------------------------------------------------------------------
// MultiHeadAttention, softmax over HEAD axis (dim=1), bf16 MFMA pipeline.
// B=4, S=2048, DIM=1024, H=8, DH=128.
//   q = (Q WQ^T) * 1/sqrt(128)   [b,s,1024] bf16 (scale folded in epilogue)
//   k =  K WK^T                  [b,s,1024] bf16
//   vt = (V WV^T) transposed ->  [b,h,dh,s] bf16 (epilogue transpose)
//   P[bloc,h,q,k] = exp(sT)/sum_h exp  via qk_head_softmax v3:
//     64k x 128q tile; TWO passes over heads (recompute QK on pass 2 --
//     MFMA is cheap, registers are not): pass 1 accumulates den in regs,
//     pass 2 recomputes scores bitwise-identically, normalizes, stores via
//     LDS transpose (coalesced 128B rows). No e8 retention -> no spill.
//   ctx = P·V via pv_gemm (pure GEMM), out = ctx WO^T fp32 -> d_out
// ---------------------------------------------------------------------------

typedef __attribute__((ext_vector_type(8))) __bf16 bf16x8;
typedef __attribute__((ext_vector_type(4))) __bf16 bf16x4;
typedef __attribute__((ext_vector_type(4))) float  f32x4;

__device__ __forceinline__ f32x4 mfma16(bf16x8 a, bf16x8 b, f32x4 c) {
    return __builtin_amdgcn_mfma_f32_16x16x32_bf16(a, b, c, 0, 0, 0);
}

// async global->LDS, 16B per lane; LDS dest must be wave-uniform-base + lane*16
__device__ __forceinline__ void cp16(void* lds, const void* g) {
    __builtin_amdgcn_global_load_lds(
        (__attribute__((address_space(1))) void*)(void*)(const_cast<void*>(g)),
        (__attribute__((address_space(3))) void*)lds,
        16, 0, 0);
}

// ---------------------------------------------------------------------------
__global__ void cast_f32_to_bf16(const float* __restrict__ src,
                                 __bf16* __restrict__ dst, int n4) {
    int i = blockIdx.x * blockDim.x + threadIdx.x;
    const int stride = gridDim.x * blockDim.x;
    for (; i < n4; i += stride) {
        float4 f = ((const float4*)src)[i];
        bf16x4 o;
        o[0] = (__bf16)f.x; o[1] = (__bf16)f.y; o[2] = (__bf16)f.z; o[3] = (__bf16)f.w;
        ((bf16x4*)dst)[i] = o;
    }
}

// 4 weight tensors in one launch (saves 3 launch overheads)
__global__ void cast4_f32_to_bf16(const float* __restrict__ s0, __bf16* __restrict__ d0,
                                  const float* __restrict__ s1, __bf16* __restrict__ d1,
                                  const float* __restrict__ s2, __bf16* __restrict__ d2,
                                  const float* __restrict__ s3, __bf16* __restrict__ d3,
                                  int n4) {
    const float* s = (blockIdx.y == 0) ? s0 : (blockIdx.y == 1) ? s1
                    : (blockIdx.y == 2) ? s2 : s3;
    __bf16* d = (blockIdx.y == 0) ? d0 : (blockIdx.y == 1) ? d1
               : (blockIdx.y == 2) ? d2 : d3;
    int i = blockIdx.x * blockDim.x + threadIdx.x;
    const int stride = gridDim.x * blockDim.x;
    for (; i < n4; i += stride) {
        float4 f = ((const float4*)s)[i];
        bf16x4 o;
        o[0] = (__bf16)f.x; o[1] = (__bf16)f.y; o[2] = (__bf16)f.z; o[3] = (__bf16)f.w;
        ((bf16x4*)d)[i] = o;
    }
}

// ---------------------------------------------------------------------------
// C[8192,1024] = A[8192,1024] * Bt[1024,1024]^T   (Bt stored [N,K] row-major)
// MODE 0: bf16 out, natural [m,n], * scale
// MODE 1: f32 out, natural [m,n]
// MODE 2: bf16 out, v-transpose: out[((b*8+h)*128+dh)*2048 + s]
template<int MODE>
__global__ __launch_bounds__(256, 2) void gemm_bt(const __bf16* __restrict__ A,
                                                  const __bf16* __restrict__ Bt,
                                                  void* __restrict__ out,
                                                  float scale)
{
    __shared__ __bf16 As[128 * 32];
    __shared__ __bf16 Bs[128 * 32];
    const int tid  = threadIdx.x;
    const int lane = tid & 63;
    const int u = lane >> 4, v = lane & 15;   // quad, col-in-tile
    const int w = tid >> 6;
    const int wm = (w >> 1) * 64, wn = (w & 1) * 64;
    const long tM = (long)blockIdx.y * 128;
    const int  tN = blockIdx.x * 128;

    f32x4 acc[4][4];
#pragma unroll
    for (int i = 0; i < 4; ++i)
#pragma unroll
        for (int j = 0; j < 4; ++j) acc[i][j] = (f32x4){0.f, 0.f, 0.f, 0.f};

    const int c0 = tid, c1 = tid + 256;
    const int ar0 = c0 >> 2, ak0 = (c0 & 3) * 8;
    const int ar1 = c1 >> 2, ak1 = (c1 & 3) * 8;

    const __bf16* Ab = A  + tM * 1024;
    const __bf16* Bb = Bt + (long)tN * 1024;

    for (int k0 = 0; k0 < 1024; k0 += 32) {
        __syncthreads();
        cp16(&As[ar0 * 32 + ak0], Ab + (long)ar0 * 1024 + k0 + ak0);
        cp16(&As[ar1 * 32 + ak1], Ab + (long)ar1 * 1024 + k0 + ak1);
        cp16(&Bs[ar0 * 32 + ak0], Bb + (long)ar0 * 1024 + k0 + ak0);
        cp16(&Bs[ar1 * 32 + ak1], Bb + (long)ar1 * 1024 + k0 + ak1);
        __syncthreads();

        bf16x8 af[4], bfr[4];
#pragma unroll
        for (int i = 0; i < 4; ++i)
            af[i] = *(const bf16x8*)&As[(wm + i * 16 + v) * 32 + u * 8];
#pragma unroll
        for (int j = 0; j < 4; ++j)
            bfr[j] = *(const bf16x8*)&Bs[(wn + j * 16 + v) * 32 + u * 8];
#pragma unroll
        for (int i = 0; i < 4; ++i)
#pragma unroll
            for (int j = 0; j < 4; ++j)
                acc[i][j] = mfma16(af[i], bfr[j], acc[i][j]);
    }

#pragma unroll
    for (int i = 0; i < 4; ++i) {
#pragma unroll
        for (int j = 0; j < 4; ++j) {
            const long row0 = tM + wm + i * 16 + u * 4;      // + r
            const int  col  = tN + wn + j * 16 + v;
            if (MODE == 0) {
                __bf16* o = (__bf16*)out;
#pragma unroll
                for (int r = 0; r < 4; ++r)
                    o[(row0 + r) * 1024 + col] = (__bf16)(acc[i][j][r] * scale);
            } else if (MODE == 1) {
                float* o = (float*)out;
#pragma unroll
                for (int r = 0; r < 4; ++r)
                    o[(row0 + r) * 1024 + col] = acc[i][j][r];
            } else {
                __bf16* o = (__bf16*)out;
                const int bidx = (int)(row0 >> 11);
                const int s    = (int)(row0 & 2047);          // 4-aligned
                const int h = col >> 7, dh = col & 127;
                bf16x4 pk;
#pragma unroll
                for (int r = 0; r < 4; ++r) pk[r] = (__bf16)acc[i][j][r];
                *(bf16x4*)&o[((long)(bidx * 8 + h) * 128 + dh) * 2048 + s] = pk;
            }
        }
    }
}

// ---------------------------------------------------------------------------
// qk_head_softmax v3: one (b, 64k x 128q) tile, all 8 heads, two passes.
// Pass 1: per head, sT[k][q] GEMM slice (Kdim=128, 4 BK-iters); den += exp
// at fixed (k,q) register positions. Pass 2: recompute scores (identical
// MFMA sequence on identical staged data -> bitwise-equal), p = exp * rinv,
// store P[bloc][h][q][k] via LDS transpose -> contiguous 128B row chunks.
// No cross-head register retention -> no spill; LDS 29 KB, 4 blocks/CU.
__global__ __launch_bounds__(256, 4) void qk_head_softmax(
    const __bf16* __restrict__ kp, const __bf16* __restrict__ qp,
    __bf16* __restrict__ P, int b_base, int q_base)
{
    __shared__ __bf16 As[64 * 32];     // 4 KB
    __shared__ __bf16 Bs[128 * 32];    // 8 KB
    __shared__ __bf16 tb[128 * 68];    // 17 KB transpose buffer
    const int tid  = threadIdx.x;
    const int lane = tid & 63;
    const int u = lane >> 4, v = lane & 15;
    const int w = tid >> 6;
    const int wm = (w >> 1) * 32, wn = (w & 1) * 64;   // 2x2 waves, 64k x 128q
    const int bloc = blockIdx.z;
    const int b    = b_base + bloc;
    const int k0   = blockIdx.x * 64;             // M-tile = 64 keys
    const int q0l  = blockIdx.y * 128;            // N-tile = 128 queries (local)
    const int q0g  = q_base + q0l;
    const long Cq  = (long)gridDim.y * 128;

    // staging: As 64x32 (1 chunk/thread), Bs 128x32 (2 chunks/thread)
    const int ar0 = tid >> 2, ak0 = (tid & 3) * 8;
    const int ar1 = ar0 + 64, ak1 = ak0;

    const __bf16* Ka = kp + ((long)b * 2048 + k0) * 1024;
    const __bf16* Qa = qp + ((long)b * 2048 + q0g) * 1024;

    f32x4 den[2][4];
#pragma unroll
    for (int i = 0; i < 2; ++i)
#pragma unroll
        for (int j = 0; j < 4; ++j) den[i][j] = (f32x4){0.f, 0.f, 0.f, 0.f};

    // ---- pass 1: denominator only ----
#pragma unroll 1
    for (int h = 0; h < 8; ++h) {
        f32x4 acc[2][4];
#pragma unroll
        for (int i = 0; i < 2; ++i)
#pragma unroll
            for (int j = 0; j < 4; ++j) acc[i][j] = (f32x4){0.f, 0.f, 0.f, 0.f};

#pragma unroll
        for (int kb = 0; kb < 4; ++kb) {
            const int co = h * 128 + kb * 32;
            __syncthreads();
            cp16(&As[ar0 * 32 + ak0], Ka + (long)ar0 * 1024 + co + ak0);
            cp16(&Bs[ar0 * 32 + ak0], Qa + (long)ar0 * 1024 + co + ak0);
            cp16(&Bs[ar1 * 32 + ak1], Qa + (long)ar1 * 1024 + co + ak1);
            __syncthreads();

            bf16x8 af[2], bfr[4];
#pragma unroll
            for (int i = 0; i < 2; ++i)
                af[i] = *(const bf16x8*)&As[(wm + i * 16 + v) * 32 + u * 8];
#pragma unroll
            for (int j = 0; j < 4; ++j)
                bfr[j] = *(const bf16x8*)&Bs[(wn + j * 16 + v) * 32 + u * 8];
#pragma unroll
            for (int i = 0; i < 2; ++i)
#pragma unroll
                for (int j = 0; j < 4; ++j)
                    acc[i][j] = mfma16(af[i], bfr[j], acc[i][j]);
        }
#pragma unroll
        for (int i = 0; i < 2; ++i)
#pragma unroll
            for (int j = 0; j < 4; ++j)
#pragma unroll
                for (int r = 0; r < 4; ++r)
                    den[i][j][r] += __expf(acc[i][j][r]);
    }

    // rinv in place
#pragma unroll
    for (int i = 0; i < 2; ++i)
#pragma unroll
        for (int j = 0; j < 4; ++j)
#pragma unroll
            for (int r = 0; r < 4; ++r) den[i][j][r] = 1.0f / den[i][j][r];

    // ---- pass 2: recompute, normalize, store ----
#pragma unroll 1
    for (int h = 0; h < 8; ++h) {
        f32x4 acc[2][4];
#pragma unroll
        for (int i = 0; i < 2; ++i)
#pragma unroll
            for (int j = 0; j < 4; ++j) acc[i][j] = (f32x4){0.f, 0.f, 0.f, 0.f};

#pragma unroll
        for (int kb = 0; kb < 4; ++kb) {
            const int co = h * 128 + kb * 32;
            __syncthreads();
            cp16(&As[ar0 * 32 + ak0], Ka + (long)ar0 * 1024 + co + ak0);
            cp16(&Bs[ar0 * 32 + ak0], Qa + (long)ar0 * 1024 + co + ak0);
            cp16(&Bs[ar1 * 32 + ak1], Qa + (long)ar1 * 1024 + co + ak1);
            __syncthreads();

            bf16x8 af[2], bfr[4];
#pragma unroll
            for (int i = 0; i < 2; ++i)
                af[i] = *(const bf16x8*)&As[(wm + i * 16 + v) * 32 + u * 8];
#pragma unroll
            for (int j = 0; j < 4; ++j)
                bfr[j] = *(const bf16x8*)&Bs[(wn + j * 16 + v) * 32 + u * 8];
#pragma unroll
            for (int i = 0; i < 2; ++i)
#pragma unroll
                for (int j = 0; j < 4; ++j)
                    acc[i][j] = mfma16(af[i], bfr[j], acc[i][j]);
        }
        // normalize into LDS transpose buffer (numerics match round 3/4:
        // bf16(f32(bf16(e)) * rinv) -- e rounded through bf16 first)
        __syncthreads();   // prior head's tb reads complete
#pragma unroll
        for (int i = 0; i < 2; ++i)
#pragma unroll
            for (int j = 0; j < 4; ++j) {
                const int kc = wm + i * 16 + u * 4;   // key (tile-local, 0..63)
                const int qr = wn + j * 16 + v;       // query (tile-local)
                bf16x4 o;
#pragma unroll
                for (int r = 0; r < 4; ++r) {
                    float e = (float)(__bf16)__expf(acc[i][j][r]);
                    o[r] = (__bf16)(e * den[i][j][r]);
                }
                *(bf16x4*)&tb[qr * 68 + kc] = o;
            }
        __syncthreads();
        __bf16* Ph = P + ((long)(bloc * 8 + h) * Cq + q0l) * 2048 + k0;
#pragma unroll
        for (int p = 0; p < 4; ++p) {
            const int qq = p * 32 + (tid >> 3);       // 32 q-rows per pass
            const int kk = (tid & 7) * 8;             // 8 lanes x 16B = 128B row
            *(bf16x8*)&Ph[(long)qq * 2048 + kk] = *(const bf16x8*)&tb[qq * 68 + kk];
        }
    }
}

// ---------------------------------------------------------------------------
// ctxT[dh][q] = sum_k vt[b,h,dh,k] * P[bloc,h,q,k]  (Kdim=2048, 64 BK-iters)
// A = vt rows (dh, stride 2048), Bt = P rows (q, stride 2048).
// Epilogue stores ctx in concat layout [b][q][h*128+dh] via bf16x4.
__global__ __launch_bounds__(256, 2) void pv_gemm(
    const __bf16* __restrict__ vt, const __bf16* __restrict__ P,
    __bf16* __restrict__ ctx, int b_base, int q_base)
{
    __shared__ __bf16 As[128 * 32];
    __shared__ __bf16 Bs[128 * 32];
    const int tid  = threadIdx.x;
    const int lane = tid & 63;
    const int u = lane >> 4, v = lane & 15;
    const int w = tid >> 6;
    const int wm = (w >> 1) * 64, wn = (w & 1) * 64;
    const int bhl  = blockIdx.y;                  // bloc*8 + h
    const int bloc = bhl >> 3, h = bhl & 7;
    const int b    = b_base + bloc;
    const int q0l  = blockIdx.x * 128;
    const int q0g  = q_base + q0l;
    const long Cq  = (long)gridDim.x * 128;

    const int c0 = tid, c1 = tid + 256;
    const int ar0 = c0 >> 2, ak0 = (c0 & 3) * 8;
    const int ar1 = c1 >> 2, ak1 = (c1 & 3) * 8;

    const __bf16* Ab = vt + (long)(b * 8 + h) * 128 * 2048;
    const __bf16* Bb = P  + ((long)(bloc * 8 + h) * Cq + q0l) * 2048;

    f32x4 acc[4][4];
#pragma unroll
    for (int i = 0; i < 4; ++i)
#pragma unroll
        for (int j = 0; j < 4; ++j) acc[i][j] = (f32x4){0.f, 0.f, 0.f, 0.f};

    for (int k0 = 0; k0 < 2048; k0 += 32) {
        __syncthreads();
        cp16(&As[ar0 * 32 + ak0], Ab + (long)ar0 * 2048 + k0 + ak0);
        cp16(&As[ar1 * 32 + ak1], Ab + (long)ar1 * 2048 + k0 + ak1);
        cp16(&Bs[ar0 * 32 + ak0], Bb + (long)ar0 * 2048 + k0 + ak0);
        cp16(&Bs[ar1 * 32 + ak1], Bb + (long)ar1 * 2048 + k0 + ak1);
        __syncthreads();

        bf16x8 af[4], bfr[4];
#pragma unroll
        for (int i = 0; i < 4; ++i)
            af[i] = *(const bf16x8*)&As[(wm + i * 16 + v) * 32 + u * 8];
#pragma unroll
        for (int j = 0; j < 4; ++j)
            bfr[j] = *(const bf16x8*)&Bs[(wn + j * 16 + v) * 32 + u * 8];
#pragma unroll
        for (int i = 0; i < 4; ++i)
#pragma unroll
            for (int j = 0; j < 4; ++j)
                acc[i][j] = mfma16(af[i], bfr[j], acc[i][j]);
    }

#pragma unroll
    for (int i = 0; i < 4; ++i) {
#pragma unroll
        for (int j = 0; j < 4; ++j) {
            const int dh0 = wm + i * 16 + u * 4;          // 4-consec feature
            const int q   = q0g + wn + j * 16 + v;
            bf16x4 pk;
#pragma unroll
            for (int r = 0; r < 4; ++r) pk[r] = (__bf16)acc[i][j][r];
            *(bf16x4*)&ctx[((long)b * 2048 + q) * 1024 + h * 128 + dh0] = pk;
        }
    }
}

// ---------------------------------------------------------------------------
// Fallback (round-1 fused attention) if ws can't hold even the smallest P.
__global__ __launch_bounds__(256, 2) void attn_softmax_head(
    const __bf16* __restrict__ qp, const __bf16* __restrict__ kp,
    const __bf16* __restrict__ vt, __bf16* __restrict__ ctx)
{
    __shared__ float part[8 * 256];
    __shared__ float pb[4][2][16 * 33];

    const int tid  = threadIdx.x;
    const int lane = tid & 63;
    const int w = tid >> 6;
    const int u = lane >> 4, v = lane & 15;
    const int b  = blockIdx.y;
    const int q0 = blockIdx.x * 16;

    const long qoff = ((long)b * 2048 + q0 + v) * 1024;
    bf16x8 qf[2][4];
#pragma unroll
    for (int hh = 0; hh < 2; ++hh) {
        const int h = 2 * w + hh;
#pragma unroll
        for (int kk = 0; kk < 4; ++kk)
            qf[hh][kk] = *(const bf16x8*)(qp + qoff + h * 128 + kk * 32 + u * 8);
    }

    f32x4 acc[2][8];
#pragma unroll
    for (int hh = 0; hh < 2; ++hh)
#pragma unroll
        for (int dt = 0; dt < 8; ++dt) acc[hh][dt] = (f32x4){0.f, 0.f, 0.f, 0.f};

    for (int kt = 0; kt < 2048; kt += 32) {
        float e[2][2][4];
#pragma unroll
        for (int hh = 0; hh < 2; ++hh) {
            const int h = 2 * w + hh;
#pragma unroll
            for (int t = 0; t < 2; ++t) {
                f32x4 s = (f32x4){0.f, 0.f, 0.f, 0.f};
                const __bf16* kb = kp + ((long)b * 2048 + kt + t * 16 + v) * 1024
                                      + h * 128 + u * 8;
#pragma unroll
                for (int kk = 0; kk < 4; ++kk)
                    s = mfma16(*(const bf16x8*)(kb + kk * 32), qf[hh][kk], s);
#pragma unroll
                for (int r = 0; r < 4; ++r) e[hh][t][r] = __expf(s[r]);
            }
        }
#pragma unroll
        for (int t = 0; t < 2; ++t)
#pragma unroll
            for (int r = 0; r < 4; ++r)
                part[(t * 4 + r) * 256 + w * 64 + lane] = e[0][t][r] + e[1][t][r];
        __syncthreads();
#pragma unroll
        for (int t = 0; t < 2; ++t)
#pragma unroll
            for (int r = 0; r < 4; ++r) {
                const int j = (t * 4 + r) * 256 + lane;
                const float den = part[j] + part[j + 64] + part[j + 128] + part[j + 192];
                const float rinv = 1.0f / den;
                const int kl = t * 16 + u * 4 + r;
                pb[w][0][v * 33 + kl] = e[0][t][r] * rinv;
                pb[w][1][v * 33 + kl] = e[1][t][r] * rinv;
            }
        bf16x8 pf[2];
#pragma unroll
        for (int hh = 0; hh < 2; ++hh)
#pragma unroll
            for (int jj = 0; jj < 8; ++jj)
                pf[hh][jj] = (__bf16)pb[w][hh][v * 33 + u * 8 + jj];
#pragma unroll
        for (int hh = 0; hh < 2; ++hh) {
            const int h = 2 * w + hh;
            const __bf16* vb = vt + ((long)(b * 8 + h) * 128 + v) * 2048 + kt + u * 8;
#pragma unroll
            for (int dt = 0; dt < 8; ++dt)
                acc[hh][dt] = mfma16(*(const bf16x8*)(vb + (long)dt * 16 * 2048),
                                     pf[hh], acc[hh][dt]);
        }
        __syncthreads();
    }

#pragma unroll
    for (int hh = 0; hh < 2; ++hh) {
        const int h = 2 * w + hh;
#pragma unroll
        for (int dt = 0; dt < 8; ++dt) {
            bf16x4 o;
#pragma unroll
            for (int r = 0; r < 4; ++r) o[r] = (__bf16)acc[hh][dt][r];
            *(bf16x4*)(ctx + ((long)b * 2048 + q0 + v) * 1024
                           + h * 128 + dt * 16 + u * 4) = o;
        }
    }
}

// ---------------------------------------------------------------------------
extern "C" void kernel_launch(void* const* d_in, const int* in_sizes, int n_in,
                              void* d_out, int out_size, void* d_ws, size_t ws_size,
                              hipStream_t stream)
{
    const float* Q  = (const float*)d_in[0];
    const float* K  = (const float*)d_in[1];
    const float* V  = (const float*)d_in[2];
    const float* WQ = (const float*)d_in[3];
    const float* WK = (const float*)d_in[4];
    const float* WV = (const float*)d_in[5];
    const float* WO = (const float*)d_in[6];

    // workspace layout (bf16 elems):
    //   4x 1M weights (8.4 MB) + 4x 8.4M tensors (67.1 MB) + adaptive P
    __bf16* ws = (__bf16*)d_ws;
    __bf16* wq = ws;
    __bf16* wk = wq + 1048576;
    __bf16* wv = wk + 1048576;
    __bf16* wo = wv + 1048576;
    __bf16* xb = wo + 1048576;     // cast buffer; reused as ctx
    __bf16* qp = xb + 8388608;
    __bf16* kp = qp + 8388608;
    __bf16* vt = kp + 8388608;
    __bf16* pbuf = vt + 8388608;   // P chunk buffer (size from ladder)

    const float qscale = 0.08838834764831845f;   // 1/sqrt(128)

    cast4_f32_to_bf16<<<dim3(256, 4), 256, 0, stream>>>(
        WQ, wq, WK, wk, WV, wv, WO, wo, 262144);

    dim3 gg(8, 64), gb(256);
    cast_f32_to_bf16<<<4096, 256, 0, stream>>>(Q, xb, 2097152);
    gemm_bt<0><<<gg, gb, 0, stream>>>(xb, wq, qp, qscale);
    cast_f32_to_bf16<<<4096, 256, 0, stream>>>(K, xb, 2097152);
    gemm_bt<0><<<gg, gb, 0, stream>>>(xb, wk, kp, 1.0f);
    cast_f32_to_bf16<<<4096, 256, 0, stream>>>(V, xb, 2097152);
    gemm_bt<2><<<gg, gb, 0, stream>>>(xb, wv, vt, 1.0f);

    // adaptive P sizing: (nb batches) x 8h x (C queries) x 2048 keys, bf16
    const size_t baseBytes = 37748736ULL * 2ULL;          // 75.5 MB
    const size_t avail = (ws_size > baseBytes) ? ws_size - baseBytes : 0;
    const int cfgs[6][2] = {{4,2048},{2,2048},{1,2048},{1,1024},{1,512},{1,256}};
    int nb = 0, C = 0;
    for (int c = 0; c < 6; ++c) {
        const size_t need = (size_t)cfgs[c][0] * 8 * cfgs[c][1] * 2048 * 2;
        if (need <= avail) { nb = cfgs[c][0]; C = cfgs[c][1]; break; }
    }

    if (nb) {
        for (int bb = 0; bb < 4; bb += nb)
            for (int qq = 0; qq < 2048; qq += C) {
                qk_head_softmax<<<dim3(32, C / 128, nb), gb, 0, stream>>>(
                    kp, qp, pbuf, bb, qq);
                pv_gemm<<<dim3(C / 128, nb * 8), gb, 0, stream>>>(
                    vt, pbuf, xb, bb, qq);
            }
    } else {
        attn_softmax_head<<<dim3(128, 4), gb, 0, stream>>>(qp, kp, vt, xb);
    }

    gemm_bt<1><<<gg, gb, 0, stream>>>(xb, wo, (float*)d_out, 1.0f);
}